// Round 4
// baseline (5412.988 us; speedup 1.0000x reference)
//
#include <hip/hip_runtime.h>
#include <math.h>

#define N_NODES 100000
#define N_EDGES 20000
#define NNZ     640000
#define C       256
#define ATT_H   128
#define HCOLS   640   // 256 (h0) + 256 (h1) + 128 (a1)
#define EPS     1e-5f

// ---------------- K1: degree histograms ----------------
__global__ __launch_bounds__(256)
void k_degrees(const int* __restrict__ nidx, const int* __restrict__ eidx,
               float* __restrict__ deg_e, float* __restrict__ deg_v) {
    int j = blockIdx.x * blockDim.x + threadIdx.x;
    if (j < NNZ) {
        atomicAdd(&deg_e[eidx[j]], 1.0f);
        atomicAdd(&deg_v[nidx[j]], 1.0f);
    }
}

__global__ __launch_bounds__(256)
void k_invert(float* __restrict__ deg, int n) {
    int i = blockIdx.x * blockDim.x + threadIdx.x;
    if (i < n) { float d = deg[i]; deg[i] = d > 0.f ? 1.f / d : 0.f; }
}

// ---------------- K2: node -> edge scatter (agg_e += x[node]) ----------------
// 64 lanes per incidence entry, 4 channels each (float4 gather, 4 atomics)
__global__ __launch_bounds__(256)
void k_scatter_e(const int* __restrict__ nidx, const int* __restrict__ eidx,
                 const float* __restrict__ x, float* __restrict__ agg_e) {
    int j = blockIdx.x * 4 + (threadIdx.x >> 6);
    int lane = threadIdx.x & 63;
    int n = nidx[j], e = eidx[j];
    const float4 v = *reinterpret_cast<const float4*>(x + (size_t)n * C + lane * 4);
    float* dst = agg_e + (size_t)e * C + lane * 4;
    atomicAdd(dst + 0, v.x);
    atomicAdd(dst + 1, v.y);
    atomicAdd(dst + 2, v.z);
    atomicAdd(dst + 3, v.w);
}

// ---------------- K3: edge -> node scatter (agg_v += Binv[e]*agg_e[e]) -------
__global__ __launch_bounds__(256)
void k_scatter_v(const int* __restrict__ nidx, const int* __restrict__ eidx,
                 const float* __restrict__ agg_e, const float* __restrict__ Binv,
                 float* __restrict__ agg_v) {
    int j = blockIdx.x * 4 + (threadIdx.x >> 6);
    int lane = threadIdx.x & 63;
    int n = nidx[j], e = eidx[j];
    float bi = Binv[e];
    const float4 v = *reinterpret_cast<const float4*>(agg_e + (size_t)e * C + lane * 4);
    float* dst = agg_v + (size_t)n * C + lane * 4;
    atomicAdd(dst + 0, v.x * bi);
    atomicAdd(dst + 1, v.y * bi);
    atomicAdd(dst + 2, v.z * bi);
    atomicAdd(dst + 3, v.w * bi);
}

// ---------------- K4: fused weight matrix Wcat [256][640] --------------------
// cols [0,256): conv_W0 @ tr_W0 ; [256,512): conv_W1 @ tr_W1 ;
// cols [512,640): 0.5*(conv_W0+conv_W1) @ attn_W1
__global__ __launch_bounds__(256)
void k_wcat(const float* __restrict__ convW, const float* __restrict__ trW,
            const float* __restrict__ attnW1, float* __restrict__ Wcat) {
    int tid = blockIdx.x * blockDim.x + threadIdx.x;
    if (tid >= C * HCOLS) return;
    int k = tid / HCOLS, j = tid % HCOLS;
    float acc = 0.f;
    if (j < C) {
        for (int m = 0; m < C; m++) acc += convW[k * C + m] * trW[m * C + j];
    } else if (j < 2 * C) {
        int j2 = j - C;
        for (int m = 0; m < C; m++) acc += convW[C * C + k * C + m] * trW[C * C + m * C + j2];
    } else {
        int ja = j - 2 * C;
        for (int m = 0; m < C; m++)
            acc += 0.5f * (convW[k * C + m] + convW[C * C + k * C + m]) * attnW1[m * ATT_H + ja];
    }
    Wcat[(size_t)k * HCOLS + j] = acc;
}

// fused bias bcat [640]
__global__ __launch_bounds__(640)
void k_bcat(const float* __restrict__ convb, const float* __restrict__ trb,
            const float* __restrict__ trW, const float* __restrict__ attnW1,
            const float* __restrict__ attnb1, float* __restrict__ bcat) {
    int j = threadIdx.x;
    if (j >= HCOLS) return;
    float acc = 0.f;
    if (j < C) {
        for (int m = 0; m < C; m++) acc += convb[m] * trW[m * C + j];
        acc += trb[j];
    } else if (j < 2 * C) {
        int j2 = j - C;
        for (int m = 0; m < C; m++) acc += convb[C + m] * trW[C * C + m * C + j2];
        acc += trb[C + j2];
    } else {
        int ja = j - 2 * C;
        for (int m = 0; m < C; m++)
            acc += 0.5f * (convb[m] + convb[C + m]) * attnW1[m * ATT_H + ja];
        acc += attnb1[ja];
    }
    bcat[j] = acc;
}

// ---------------- K5: GEMM  h = (Dinv ⊙ agg_v) @ Wcat + bcat ----------------
// BM=128, BN=64, BK=32, 256 threads (16x16), 8x4 micro-tile
#define BM 128
#define BN 64
#define BK 32
__global__ __launch_bounds__(256)
void k_gemm(const float* __restrict__ A, const float* __restrict__ Dinv,
            const float* __restrict__ Wcat, const float* __restrict__ bcat,
            float* __restrict__ h) {
    __shared__ float As[BK][BM + 4];  // [32][132]
    __shared__ float Bs[BK][BN + 4];  // [32][68]
    const int t = threadIdx.x;
    const int tx = t & 15, ty = t >> 4;
    const int by = blockIdx.x / 10;
    const int bx = blockIdx.x % 10;
    const int row0 = by * BM;
    const int col0 = bx * BN;

    float acc[8][4];
#pragma unroll
    for (int i = 0; i < 8; i++)
#pragma unroll
        for (int j = 0; j < 4; j++) acc[i][j] = 0.f;

    for (int kb = 0; kb < C; kb += BK) {
        // A tile: 128x32 = 1024 float4, 4 per thread (with Dinv row scaling)
#pragma unroll
        for (int i = 0; i < 4; i++) {
            int f4 = t + i * 256;
            int k4 = f4 & 7;
            int r  = f4 >> 3;
            int row = row0 + r;
            float4 v = make_float4(0.f, 0.f, 0.f, 0.f);
            if (row < N_NODES) {
                v = *reinterpret_cast<const float4*>(A + (size_t)row * C + kb + k4 * 4);
                float s = Dinv[row];
                v.x *= s; v.y *= s; v.z *= s; v.w *= s;
            }
            As[k4 * 4 + 0][r] = v.x;
            As[k4 * 4 + 1][r] = v.y;
            As[k4 * 4 + 2][r] = v.z;
            As[k4 * 4 + 3][r] = v.w;
        }
        // B tile: 32x64 = 512 float4, 2 per thread
#pragma unroll
        for (int i = 0; i < 2; i++) {
            int f4 = t + i * 256;
            int c4 = f4 & 15;
            int kk = f4 >> 4;
            float4 v = *reinterpret_cast<const float4*>(
                Wcat + (size_t)(kb + kk) * HCOLS + col0 + c4 * 4);
            *reinterpret_cast<float4*>(&Bs[kk][c4 * 4]) = v;
        }
        __syncthreads();
#pragma unroll
        for (int kk = 0; kk < BK; ++kk) {
            float4 b4 = *reinterpret_cast<const float4*>(&Bs[kk][tx * 4]);
            float4 a0 = *reinterpret_cast<const float4*>(&As[kk][ty * 8]);
            float4 a1 = *reinterpret_cast<const float4*>(&As[kk][ty * 8 + 4]);
            float a[8] = {a0.x, a0.y, a0.z, a0.w, a1.x, a1.y, a1.z, a1.w};
            float b[4] = {b4.x, b4.y, b4.z, b4.w};
#pragma unroll
            for (int i = 0; i < 8; i++)
#pragma unroll
                for (int j = 0; j < 4; j++) acc[i][j] += a[i] * b[j];
        }
        __syncthreads();
    }
    float4 bc = *reinterpret_cast<const float4*>(bcat + col0 + tx * 4);
#pragma unroll
    for (int i = 0; i < 8; i++) {
        int row = row0 + ty * 8 + i;
        if (row < N_NODES) {
            float4 o;
            o.x = acc[i][0] + bc.x;
            o.y = acc[i][1] + bc.y;
            o.z = acc[i][2] + bc.z;
            o.w = acc[i][3] + bc.w;
            *reinterpret_cast<float4*>(h + (size_t)row * HCOLS + col0 + tx * 4) = o;
        }
    }
}

// ---------------- K6: dynamic weights (softmax of attn logits, mean) ---------
__global__ __launch_bounds__(256)
void k_dynw(const float* __restrict__ h, const float* __restrict__ W2,
            const float* __restrict__ b2, float* __restrict__ dsum) {
    int r = blockIdx.x * blockDim.x + threadIdx.x;
    float p0 = 0.f, p1 = 0.f;
    if (r < N_NODES) {
        float L0 = b2[0], L1 = b2[1];
        const float* hr = h + (size_t)r * HCOLS + 512;
        for (int m = 0; m < ATT_H; m++) {
            float v = fmaxf(hr[m], 0.f);
            L0 += v * W2[m * 2 + 0];
            L1 += v * W2[m * 2 + 1];
        }
        float mx = fmaxf(L0, L1);
        float e0 = expf(L0 - mx), e1 = expf(L1 - mx);
        float inv = 1.f / (e0 + e1);
        p0 = e0 * inv; p1 = e1 * inv;
    }
#pragma unroll
    for (int off = 32; off; off >>= 1) {
        p0 += __shfl_down(p0, off);
        p1 += __shfl_down(p1, off);
    }
    __shared__ float red[4][2];
    int wave = threadIdx.x >> 6, lane = threadIdx.x & 63;
    if (lane == 0) { red[wave][0] = p0; red[wave][1] = p1; }
    __syncthreads();
    if (threadIdx.x == 0) {
        atomicAdd(&dsum[0], red[0][0] + red[1][0] + red[2][0] + red[3][0]);
        atomicAdd(&dsum[1], red[0][1] + red[1][1] + red[2][1] + red[3][1]);
    }
}

// ---------------- K7: LayerNorm + ReLU + weighted combine -------------------
__global__ __launch_bounds__(256)
void k_final(const float* __restrict__ h, const float* __restrict__ ln_g,
             const float* __restrict__ ln_b, const float* __restrict__ sw,
             const float* __restrict__ dsum, float* __restrict__ out) {
    int r = blockIdx.x;
    int c = threadIdx.x;
    float h0 = h[(size_t)r * HCOLS + c];
    float h1 = h[(size_t)r * HCOLS + 256 + c];
    float s0 = h0, q0 = h0 * h0, s1 = h1, q1 = h1 * h1;
#pragma unroll
    for (int off = 32; off; off >>= 1) {
        s0 += __shfl_down(s0, off); q0 += __shfl_down(q0, off);
        s1 += __shfl_down(s1, off); q1 += __shfl_down(q1, off);
    }
    __shared__ float red[4][4];
    int wave = c >> 6, lane = c & 63;
    if (lane == 0) {
        red[wave][0] = s0; red[wave][1] = q0;
        red[wave][2] = s1; red[wave][3] = q1;
    }
    __syncthreads();
    s0 = red[0][0] + red[1][0] + red[2][0] + red[3][0];
    q0 = red[0][1] + red[1][1] + red[2][1] + red[3][1];
    s1 = red[0][2] + red[1][2] + red[2][2] + red[3][2];
    q1 = red[0][3] + red[1][3] + red[2][3] + red[3][3];
    const float invC = 1.f / 256.f;
    float mu0 = s0 * invC, mu1 = s1 * invC;
    float v0 = q0 * invC - mu0 * mu0;
    float v1 = q1 * invC - mu1 * mu1;
    float rs0 = rsqrtf(v0 + EPS), rs1 = rsqrtf(v1 + EPS);
    float t0 = fmaxf((h0 - mu0) * rs0 * ln_g[c] + ln_b[c], 0.f);
    float t1 = fmaxf((h1 - mu1) * rs1 * ln_g[256 + c] + ln_b[256 + c], 0.f);
    float a0 = sw[0], a1 = sw[1];
    float mx = fmaxf(a0, a1);
    float e0 = expf(a0 - mx), e1 = expf(a1 - mx);
    float inv = 1.f / (e0 + e1);
    float w0 = 0.5f * (e0 * inv + dsum[0] * (1.f / N_NODES));
    float w1 = 0.5f * (e1 * inv + dsum[1] * (1.f / N_NODES));
    out[(size_t)r * C + c] = w0 * t0 + w1 * t1;
}

// ---------------- launch ----------------
extern "C" void kernel_launch(void* const* d_in, const int* in_sizes, int n_in,
                              void* d_out, int out_size, void* d_ws, size_t ws_size,
                              hipStream_t stream) {
    const float* x       = (const float*)d_in[0];
    const int*   he      = (const int*)d_in[1];
    const int*   nidx    = he;
    const int*   eidx    = he + NNZ;
    const float* convW   = (const float*)d_in[2];
    const float* convb   = (const float*)d_in[3];
    const float* trW     = (const float*)d_in[4];
    const float* trb     = (const float*)d_in[5];
    const float* ln_g    = (const float*)d_in[6];
    const float* ln_b    = (const float*)d_in[7];
    const float* sw      = (const float*)d_in[8];
    const float* attnW1  = (const float*)d_in[9];
    const float* attnb1  = (const float*)d_in[10];
    const float* attnW2  = (const float*)d_in[11];
    const float* attnb2  = (const float*)d_in[12];
    float* out = (float*)d_out;

    // workspace layout (floats)
    float* ws    = (float*)d_ws;
    float* Wcat  = ws;                       // 163840
    float* bcat  = Wcat + 163840;            // 640
    float* deg_e = bcat + 640;               // 20000 -> Binv
    float* deg_v = deg_e + 20000;            // 100000 -> Dinv
    float* dsum  = deg_v + 100000;           // 8 (2 used)
    float* agg_e = dsum + 8;                 // 5,120,000
    float* agg_v = agg_e + 5120000;          // 25,600,000
    float* h     = agg_v + 25600000;         // 64,000,000

    // zero deg_e..agg_v (contiguous): (20000+100000+8+5120000+25600000)*4 bytes
    size_t zero_bytes = (size_t)(20000 + 100000 + 8 + 5120000 + 25600000) * 4;
    hipMemsetAsync(deg_e, 0, zero_bytes, stream);

    k_degrees<<<(NNZ + 255) / 256, 256, 0, stream>>>(nidx, eidx, deg_e, deg_v);
    k_invert<<<(N_EDGES + 255) / 256, 256, 0, stream>>>(deg_e, N_EDGES);
    k_invert<<<(N_NODES + 255) / 256, 256, 0, stream>>>(deg_v, N_NODES);

    k_wcat<<<(C * HCOLS + 255) / 256, 256, 0, stream>>>(convW, trW, attnW1, Wcat);
    k_bcat<<<1, 640, 0, stream>>>(convb, trb, trW, attnW1, attnb1, bcat);

    k_scatter_e<<<NNZ / 4, 256, 0, stream>>>(nidx, eidx, x, agg_e);
    k_scatter_v<<<NNZ / 4, 256, 0, stream>>>(nidx, eidx, agg_e, deg_e, agg_v);

    int row_blocks = (N_NODES + BM - 1) / BM;   // 782
    k_gemm<<<row_blocks * 10, 256, 0, stream>>>(agg_v, deg_v, Wcat, bcat, h);

    k_dynw<<<(N_NODES + 255) / 256, 256, 0, stream>>>(h, attnW2, attnb2, dsum);

    k_final<<<N_NODES, 256, 0, stream>>>(h, ln_g, ln_b, sw, dsum, out);
}

// Round 5
// 1284.637 us; speedup vs baseline: 4.2136x; 4.2136x over previous
//
#include <hip/hip_runtime.h>
#include <math.h>

#define N_NODES 100000
#define N_EDGES 20000
#define NNZ     640000
#define C       256
#define ATT_H   128
#define HCOLS   640   // 256 (h0) + 256 (h1) + 128 (a1)
#define EPS     1e-5f

// ---------------- K1: integer degree histograms ----------------
__global__ __launch_bounds__(256)
void k_degrees(const int* __restrict__ nidx, const int* __restrict__ eidx,
               int* __restrict__ deg_e, int* __restrict__ deg_v) {
    int j = blockIdx.x * blockDim.x + threadIdx.x;
    if (j < NNZ) {
        atomicAdd(&deg_e[eidx[j]], 1);
        atomicAdd(&deg_v[nidx[j]], 1);
    }
}

// inverse of integer degree -> float (0 if empty)
__global__ __launch_bounds__(256)
void k_invert(const int* __restrict__ cnt, float* __restrict__ inv, int n) {
    int i = blockIdx.x * blockDim.x + threadIdx.x;
    if (i < n) { int d = cnt[i]; inv[i] = d > 0 ? 1.f / (float)d : 0.f; }
}

// ---------------- K2: single-block exclusive scan (n up to ~100K) ----------
__global__ __launch_bounds__(1024)
void k_scan(const int* __restrict__ cnt, int* __restrict__ start, int n) {
    __shared__ int tmp[1024];
    __shared__ int block_off;
    if (threadIdx.x == 0) block_off = 0;
    __syncthreads();
    for (int base = 0; base < n; base += 1024) {
        int i = base + threadIdx.x;
        int v = (i < n) ? cnt[i] : 0;
        tmp[threadIdx.x] = v;
        __syncthreads();
        for (int off = 1; off < 1024; off <<= 1) {
            int add = (threadIdx.x >= off) ? tmp[threadIdx.x - off] : 0;
            __syncthreads();
            tmp[threadIdx.x] += add;
            __syncthreads();
        }
        if (i < n) start[i] = block_off + tmp[threadIdx.x] - v;  // exclusive
        __syncthreads();
        if (threadIdx.x == 0) block_off += tmp[1023];
        __syncthreads();
    }
    if (threadIdx.x == 0) start[n] = block_off;
}

// ---------------- K3: fill CSR adjacency (640K int atomics) -----------------
__global__ __launch_bounds__(256)
void k_fill(const int* __restrict__ nidx, const int* __restrict__ eidx,
            const int* __restrict__ e_start, const int* __restrict__ v_start,
            int* __restrict__ cur_e, int* __restrict__ cur_v,
            int* __restrict__ sorted_node, int* __restrict__ sorted_edge) {
    int j = blockIdx.x * blockDim.x + threadIdx.x;
    if (j < NNZ) {
        int n = nidx[j], e = eidx[j];
        int pe = atomicAdd(&cur_e[e], 1);
        sorted_node[e_start[e] + pe] = n;
        int pv = atomicAdd(&cur_v[n], 1);
        sorted_edge[v_start[n] + pv] = e;
    }
}

// ---------------- K4: per-edge gather  agg_e[e] = Binv[e] * sum x[members] --
// one 64-lane wave per edge, 4 channels per lane (float4)
__global__ __launch_bounds__(256)
void k_gather_e(const int* __restrict__ sorted_node, const int* __restrict__ e_start,
                const float* __restrict__ x, const float* __restrict__ Binv,
                float* __restrict__ agg_e) {
    int e = blockIdx.x * 4 + (threadIdx.x >> 6);
    int lane = threadIdx.x & 63;
    int s = e_start[e], t = e_start[e + 1];
    float4 acc = make_float4(0.f, 0.f, 0.f, 0.f);
    for (int p = s; p < t; ++p) {
        int n = sorted_node[p];
        const float4 v = *reinterpret_cast<const float4*>(x + (size_t)n * C + lane * 4);
        acc.x += v.x; acc.y += v.y; acc.z += v.z; acc.w += v.w;
    }
    float bi = Binv[e];
    acc.x *= bi; acc.y *= bi; acc.z *= bi; acc.w *= bi;
    *reinterpret_cast<float4*>(agg_e + (size_t)e * C + lane * 4) = acc;
}

// ---------------- K5: per-node gather  agg_v[n] = sum agg_e[its edges] ------
__global__ __launch_bounds__(256)
void k_gather_v(const int* __restrict__ sorted_edge, const int* __restrict__ v_start,
                const float* __restrict__ agg_e, float* __restrict__ agg_v) {
    int n = blockIdx.x * 4 + (threadIdx.x >> 6);
    int lane = threadIdx.x & 63;
    int s = v_start[n], t = v_start[n + 1];
    float4 acc = make_float4(0.f, 0.f, 0.f, 0.f);
    for (int p = s; p < t; ++p) {
        int e = sorted_edge[p];
        const float4 v = *reinterpret_cast<const float4*>(agg_e + (size_t)e * C + lane * 4);
        acc.x += v.x; acc.y += v.y; acc.z += v.z; acc.w += v.w;
    }
    *reinterpret_cast<float4*>(agg_v + (size_t)n * C + lane * 4) = acc;
}

// ---------------- K6: fused weight matrix Wcat [256][640] --------------------
// cols [0,256): conv_W0 @ tr_W0 ; [256,512): conv_W1 @ tr_W1 ;
// cols [512,640): 0.5*(conv_W0+conv_W1) @ attn_W1
__global__ __launch_bounds__(256)
void k_wcat(const float* __restrict__ convW, const float* __restrict__ trW,
            const float* __restrict__ attnW1, float* __restrict__ Wcat) {
    int tid = blockIdx.x * blockDim.x + threadIdx.x;
    if (tid >= C * HCOLS) return;
    int k = tid / HCOLS, j = tid % HCOLS;
    float acc = 0.f;
    if (j < C) {
        for (int m = 0; m < C; m++) acc += convW[k * C + m] * trW[m * C + j];
    } else if (j < 2 * C) {
        int j2 = j - C;
        for (int m = 0; m < C; m++) acc += convW[C * C + k * C + m] * trW[C * C + m * C + j2];
    } else {
        int ja = j - 2 * C;
        for (int m = 0; m < C; m++)
            acc += 0.5f * (convW[k * C + m] + convW[C * C + k * C + m]) * attnW1[m * ATT_H + ja];
    }
    Wcat[(size_t)k * HCOLS + j] = acc;
}

// fused bias bcat [640]
__global__ __launch_bounds__(640)
void k_bcat(const float* __restrict__ convb, const float* __restrict__ trb,
            const float* __restrict__ trW, const float* __restrict__ attnW1,
            const float* __restrict__ attnb1, float* __restrict__ bcat) {
    int j = threadIdx.x;
    if (j >= HCOLS) return;
    float acc = 0.f;
    if (j < C) {
        for (int m = 0; m < C; m++) acc += convb[m] * trW[m * C + j];
        acc += trb[j];
    } else if (j < 2 * C) {
        int j2 = j - C;
        for (int m = 0; m < C; m++) acc += convb[C + m] * trW[C * C + m * C + j2];
        acc += trb[C + j2];
    } else {
        int ja = j - 2 * C;
        for (int m = 0; m < C; m++)
            acc += 0.5f * (convb[m] + convb[C + m]) * attnW1[m * ATT_H + ja];
        acc += attnb1[ja];
    }
    bcat[j] = acc;
}

// ---------------- K7: GEMM  h = (Dinv ⊙ agg_v) @ Wcat + bcat ----------------
#define BM 128
#define BN 64
#define BK 32
__global__ __launch_bounds__(256)
void k_gemm(const float* __restrict__ A, const float* __restrict__ Dinv,
            const float* __restrict__ Wcat, const float* __restrict__ bcat,
            float* __restrict__ h) {
    __shared__ float As[BK][BM + 4];
    __shared__ float Bs[BK][BN + 4];
    const int t = threadIdx.x;
    const int tx = t & 15, ty = t >> 4;
    const int by = blockIdx.x / 10;
    const int bx = blockIdx.x % 10;
    const int row0 = by * BM;
    const int col0 = bx * BN;

    float acc[8][4];
#pragma unroll
    for (int i = 0; i < 8; i++)
#pragma unroll
        for (int j = 0; j < 4; j++) acc[i][j] = 0.f;

    for (int kb = 0; kb < C; kb += BK) {
#pragma unroll
        for (int i = 0; i < 4; i++) {
            int f4 = t + i * 256;
            int k4 = f4 & 7;
            int r  = f4 >> 3;
            int row = row0 + r;
            float4 v = make_float4(0.f, 0.f, 0.f, 0.f);
            if (row < N_NODES) {
                v = *reinterpret_cast<const float4*>(A + (size_t)row * C + kb + k4 * 4);
                float s = Dinv[row];
                v.x *= s; v.y *= s; v.z *= s; v.w *= s;
            }
            As[k4 * 4 + 0][r] = v.x;
            As[k4 * 4 + 1][r] = v.y;
            As[k4 * 4 + 2][r] = v.z;
            As[k4 * 4 + 3][r] = v.w;
        }
#pragma unroll
        for (int i = 0; i < 2; i++) {
            int f4 = t + i * 256;
            int c4 = f4 & 15;
            int kk = f4 >> 4;
            float4 v = *reinterpret_cast<const float4*>(
                Wcat + (size_t)(kb + kk) * HCOLS + col0 + c4 * 4);
            *reinterpret_cast<float4*>(&Bs[kk][c4 * 4]) = v;
        }
        __syncthreads();
#pragma unroll
        for (int kk = 0; kk < BK; ++kk) {
            float4 b4 = *reinterpret_cast<const float4*>(&Bs[kk][tx * 4]);
            float4 a0 = *reinterpret_cast<const float4*>(&As[kk][ty * 8]);
            float4 a1 = *reinterpret_cast<const float4*>(&As[kk][ty * 8 + 4]);
            float a[8] = {a0.x, a0.y, a0.z, a0.w, a1.x, a1.y, a1.z, a1.w};
            float b[4] = {b4.x, b4.y, b4.z, b4.w};
#pragma unroll
            for (int i = 0; i < 8; i++)
#pragma unroll
                for (int j = 0; j < 4; j++) acc[i][j] += a[i] * b[j];
        }
        __syncthreads();
    }
    float4 bc = *reinterpret_cast<const float4*>(bcat + col0 + tx * 4);
#pragma unroll
    for (int i = 0; i < 8; i++) {
        int row = row0 + ty * 8 + i;
        if (row < N_NODES) {
            float4 o;
            o.x = acc[i][0] + bc.x;
            o.y = acc[i][1] + bc.y;
            o.z = acc[i][2] + bc.z;
            o.w = acc[i][3] + bc.w;
            *reinterpret_cast<float4*>(h + (size_t)row * HCOLS + col0 + tx * 4) = o;
        }
    }
}

// ---------------- K8: dynamic weights (softmax of attn logits, mean) ---------
__global__ __launch_bounds__(256)
void k_dynw(const float* __restrict__ h, const float* __restrict__ W2,
            const float* __restrict__ b2, float* __restrict__ dsum) {
    int r = blockIdx.x * blockDim.x + threadIdx.x;
    float p0 = 0.f, p1 = 0.f;
    if (r < N_NODES) {
        float L0 = b2[0], L1 = b2[1];
        const float* hr = h + (size_t)r * HCOLS + 512;
        for (int m = 0; m < ATT_H; m++) {
            float v = fmaxf(hr[m], 0.f);
            L0 += v * W2[m * 2 + 0];
            L1 += v * W2[m * 2 + 1];
        }
        float mx = fmaxf(L0, L1);
        float e0 = expf(L0 - mx), e1 = expf(L1 - mx);
        float inv = 1.f / (e0 + e1);
        p0 = e0 * inv; p1 = e1 * inv;
    }
#pragma unroll
    for (int off = 32; off; off >>= 1) {
        p0 += __shfl_down(p0, off);
        p1 += __shfl_down(p1, off);
    }
    __shared__ float red[4][2];
    int wave = threadIdx.x >> 6, lane = threadIdx.x & 63;
    if (lane == 0) { red[wave][0] = p0; red[wave][1] = p1; }
    __syncthreads();
    if (threadIdx.x == 0) {
        atomicAdd(&dsum[0], red[0][0] + red[1][0] + red[2][0] + red[3][0]);
        atomicAdd(&dsum[1], red[0][1] + red[1][1] + red[2][1] + red[3][1]);
    }
}

// ---------------- K9: LayerNorm + ReLU + weighted combine -------------------
__global__ __launch_bounds__(256)
void k_final(const float* __restrict__ h, const float* __restrict__ ln_g,
             const float* __restrict__ ln_b, const float* __restrict__ sw,
             const float* __restrict__ dsum, float* __restrict__ out) {
    int r = blockIdx.x;
    int c = threadIdx.x;
    float h0 = h[(size_t)r * HCOLS + c];
    float h1 = h[(size_t)r * HCOLS + 256 + c];
    float s0 = h0, q0 = h0 * h0, s1 = h1, q1 = h1 * h1;
#pragma unroll
    for (int off = 32; off; off >>= 1) {
        s0 += __shfl_down(s0, off); q0 += __shfl_down(q0, off);
        s1 += __shfl_down(s1, off); q1 += __shfl_down(q1, off);
    }
    __shared__ float red[4][4];
    int wave = c >> 6, lane = c & 63;
    if (lane == 0) {
        red[wave][0] = s0; red[wave][1] = q0;
        red[wave][2] = s1; red[wave][3] = q1;
    }
    __syncthreads();
    s0 = red[0][0] + red[1][0] + red[2][0] + red[3][0];
    q0 = red[0][1] + red[1][1] + red[2][1] + red[3][1];
    s1 = red[0][2] + red[1][2] + red[2][2] + red[3][2];
    q1 = red[0][3] + red[1][3] + red[2][3] + red[3][3];
    const float invC = 1.f / 256.f;
    float mu0 = s0 * invC, mu1 = s1 * invC;
    float v0 = q0 * invC - mu0 * mu0;
    float v1 = q1 * invC - mu1 * mu1;
    float rs0 = rsqrtf(v0 + EPS), rs1 = rsqrtf(v1 + EPS);
    float t0 = fmaxf((h0 - mu0) * rs0 * ln_g[c] + ln_b[c], 0.f);
    float t1 = fmaxf((h1 - mu1) * rs1 * ln_g[256 + c] + ln_b[256 + c], 0.f);
    float a0 = sw[0], a1 = sw[1];
    float mx = fmaxf(a0, a1);
    float e0 = expf(a0 - mx), e1 = expf(a1 - mx);
    float inv = 1.f / (e0 + e1);
    float w0 = 0.5f * (e0 * inv + dsum[0] * (1.f / N_NODES));
    float w1 = 0.5f * (e1 * inv + dsum[1] * (1.f / N_NODES));
    out[(size_t)r * C + c] = w0 * t0 + w1 * t1;
}

// ---------------- launch ----------------
extern "C" void kernel_launch(void* const* d_in, const int* in_sizes, int n_in,
                              void* d_out, int out_size, void* d_ws, size_t ws_size,
                              hipStream_t stream) {
    const float* x       = (const float*)d_in[0];
    const int*   he      = (const int*)d_in[1];
    const int*   nidx    = he;
    const int*   eidx    = he + NNZ;
    const float* convW   = (const float*)d_in[2];
    const float* convb   = (const float*)d_in[3];
    const float* trW     = (const float*)d_in[4];
    const float* trb     = (const float*)d_in[5];
    const float* ln_g    = (const float*)d_in[6];
    const float* ln_b    = (const float*)d_in[7];
    const float* sw      = (const float*)d_in[8];
    const float* attnW1  = (const float*)d_in[9];
    const float* attnb1  = (const float*)d_in[10];
    const float* attnW2  = (const float*)d_in[11];
    const float* attnb2  = (const float*)d_in[12];
    float* out = (float*)d_out;

    // workspace layout
    float* ws     = (float*)d_ws;
    float* Wcat   = ws;                         // 163840 f
    float* bcat   = Wcat + 163840;              // 640 f
    float* Binv   = bcat + 640;                 // 20000 f
    float* Dinv   = Binv + 20000;               // 100000 f
    float* dsum   = Dinv + 100000;              // 8 f
    int*   deg_e  = (int*)(dsum + 8);           // 20000 i
    int*   deg_v  = deg_e + 20000;              // 100000 i
    int*   e_start= deg_v + 100000;             // 20004 i
    int*   v_start= e_start + 20004;            // 100004 i
    int*   cur_e  = v_start + 100004;           // 20000 i
    int*   cur_v  = cur_e + 20000;              // 100000 i
    int*   s_node = cur_v + 100000;             // 640000 i
    int*   s_edge = s_node + 640000;            // 640000 i
    float* agg_e  = (float*)(s_edge + 640000);  // 5,120,000 f
    float* agg_v  = agg_e + 5120000;            // 25,600,000 f
    float* h      = agg_v + 25600000;           // 64,000,000 f

    // zero: dsum + int region (deg/cursors); CSR starts get overwritten anyway
    size_t zero_bytes = (size_t)(8 + 20000 + 100000 + 20004 + 100004
                                 + 20000 + 100000) * 4;
    hipMemsetAsync(dsum, 0, zero_bytes, stream);

    k_degrees<<<(NNZ + 255) / 256, 256, 0, stream>>>(nidx, eidx, deg_e, deg_v);
    k_invert<<<(N_EDGES + 255) / 256, 256, 0, stream>>>(deg_e, Binv, N_EDGES);
    k_invert<<<(N_NODES + 255) / 256, 256, 0, stream>>>(deg_v, Dinv, N_NODES);
    k_scan<<<1, 1024, 0, stream>>>(deg_e, e_start, N_EDGES);
    k_scan<<<1, 1024, 0, stream>>>(deg_v, v_start, N_NODES);
    k_fill<<<(NNZ + 255) / 256, 256, 0, stream>>>(nidx, eidx, e_start, v_start,
                                                  cur_e, cur_v, s_node, s_edge);

    k_wcat<<<(C * HCOLS + 255) / 256, 256, 0, stream>>>(convW, trW, attnW1, Wcat);
    k_bcat<<<1, 640, 0, stream>>>(convb, trb, trW, attnW1, attnb1, bcat);

    k_gather_e<<<N_EDGES / 4, 256, 0, stream>>>(s_node, e_start, x, Binv, agg_e);
    k_gather_v<<<N_NODES / 4, 256, 0, stream>>>(s_edge, v_start, agg_e, agg_v);

    int row_blocks = (N_NODES + BM - 1) / BM;   // 782
    k_gemm<<<row_blocks * 10, 256, 0, stream>>>(agg_v, Dinv, Wcat, bcat, h);

    k_dynw<<<(N_NODES + 255) / 256, 256, 0, stream>>>(h, attnW2, attnb2, dsum);

    k_final<<<N_NODES, 256, 0, stream>>>(h, ln_g, ln_b, sw, dsum, out);
}

// Round 6
// 892.358 us; speedup vs baseline: 6.0659x; 1.4396x over previous
//
#include <hip/hip_runtime.h>
#include <math.h>

#define N_NODES 100000
#define N_EDGES 20000
#define NNZ     640000
#define C       256
#define ATT_H   128
#define HCOLS   640   // 256 (h0) + 256 (h1) + 128 (a1)
#define HST     512   // stored h columns (attn slice consumed in-register)
#define EPS     1e-5f

// ---------------- K1: integer degree histograms ----------------
__global__ __launch_bounds__(256)
void k_degrees(const int* __restrict__ nidx, const int* __restrict__ eidx,
               int* __restrict__ deg_e, int* __restrict__ deg_v) {
    int j = blockIdx.x * blockDim.x + threadIdx.x;
    if (j < NNZ) {
        atomicAdd(&deg_e[eidx[j]], 1);
        atomicAdd(&deg_v[nidx[j]], 1);
    }
}

__global__ __launch_bounds__(256)
void k_invert(const int* __restrict__ cnt, float* __restrict__ inv, int n) {
    int i = blockIdx.x * blockDim.x + threadIdx.x;
    if (i < n) { int d = cnt[i]; inv[i] = d > 0 ? 1.f / (float)d : 0.f; }
}

// ---------------- K2: 3-phase multi-block exclusive scan --------------------
// phase 1: per-1024-chunk sums
__global__ __launch_bounds__(256)
void k_chunk_sums(const int* __restrict__ cnt, int* __restrict__ bsum, int n) {
    int base = blockIdx.x * 1024;
    int s = 0;
    for (int i = threadIdx.x; i < 1024; i += 256) {
        int g = base + i;
        s += (g < n) ? cnt[g] : 0;
    }
#pragma unroll
    for (int off = 32; off; off >>= 1) s += __shfl_down(s, off);
    __shared__ int red[4];
    int wave = threadIdx.x >> 6, lane = threadIdx.x & 63;
    if (lane == 0) red[wave] = s;
    __syncthreads();
    if (threadIdx.x == 0) bsum[blockIdx.x] = red[0] + red[1] + red[2] + red[3];
}

// phase 2: single-block exclusive scan of chunk sums (nb <= 128); writes total
__global__ __launch_bounds__(128)
void k_scan_bsum(int* __restrict__ bsum, int nb, int* __restrict__ start, int n) {
    __shared__ int tmp[128];
    int v = (threadIdx.x < nb) ? bsum[threadIdx.x] : 0;
    tmp[threadIdx.x] = v;
    __syncthreads();
    for (int off = 1; off < 128; off <<= 1) {
        int a = (threadIdx.x >= off) ? tmp[threadIdx.x - off] : 0;
        __syncthreads();
        tmp[threadIdx.x] += a;
        __syncthreads();
    }
    if (threadIdx.x < nb) bsum[threadIdx.x] = tmp[threadIdx.x] - v;  // exclusive
    if (threadIdx.x == nb - 1) start[n] = tmp[threadIdx.x];          // total
}

// phase 3: local scan per chunk + chunk offset
__global__ __launch_bounds__(1024)
void k_scan_final(const int* __restrict__ cnt, const int* __restrict__ bsum,
                  int* __restrict__ start, int n) {
    __shared__ int tmp[1024];
    int i = blockIdx.x * 1024 + threadIdx.x;
    int v = (i < n) ? cnt[i] : 0;
    tmp[threadIdx.x] = v;
    __syncthreads();
    for (int off = 1; off < 1024; off <<= 1) {
        int a = (threadIdx.x >= off) ? tmp[threadIdx.x - off] : 0;
        __syncthreads();
        tmp[threadIdx.x] += a;
        __syncthreads();
    }
    if (i < n) start[i] = bsum[blockIdx.x] + tmp[threadIdx.x] - v;  // exclusive
}

// ---------------- K3: fill CSR adjacency (640K int atomics) -----------------
__global__ __launch_bounds__(256)
void k_fill(const int* __restrict__ nidx, const int* __restrict__ eidx,
            const int* __restrict__ e_start, const int* __restrict__ v_start,
            int* __restrict__ cur_e, int* __restrict__ cur_v,
            int* __restrict__ sorted_node, int* __restrict__ sorted_edge) {
    int j = blockIdx.x * blockDim.x + threadIdx.x;
    if (j < NNZ) {
        int n = nidx[j], e = eidx[j];
        int pe = atomicAdd(&cur_e[e], 1);
        sorted_node[e_start[e] + pe] = n;
        int pv = atomicAdd(&cur_v[n], 1);
        sorted_edge[v_start[n] + pv] = e;
    }
}

// ---------------- K4: per-edge gather  agg_e[e] = Binv[e] * sum x[members] --
__global__ __launch_bounds__(256)
void k_gather_e(const int* __restrict__ sorted_node, const int* __restrict__ e_start,
                const float* __restrict__ x, const float* __restrict__ Binv,
                float* __restrict__ agg_e) {
    int e = blockIdx.x * 4 + (threadIdx.x >> 6);
    int lane = threadIdx.x & 63;
    int s = e_start[e], t = e_start[e + 1];
    float4 acc = make_float4(0.f, 0.f, 0.f, 0.f);
    for (int p = s; p < t; ++p) {
        int n = sorted_node[p];
        const float4 v = *reinterpret_cast<const float4*>(x + (size_t)n * C + lane * 4);
        acc.x += v.x; acc.y += v.y; acc.z += v.z; acc.w += v.w;
    }
    float bi = Binv[e];
    acc.x *= bi; acc.y *= bi; acc.z *= bi; acc.w *= bi;
    *reinterpret_cast<float4*>(agg_e + (size_t)e * C + lane * 4) = acc;
}

// ---------------- K5: fused weight matrix Wcat [256][640] -------------------
__global__ __launch_bounds__(256)
void k_wcat(const float* __restrict__ convW, const float* __restrict__ trW,
            const float* __restrict__ attnW1, float* __restrict__ Wcat) {
    int tid = blockIdx.x * blockDim.x + threadIdx.x;
    if (tid >= C * HCOLS) return;
    int k = tid / HCOLS, j = tid % HCOLS;
    float acc = 0.f;
    if (j < C) {
        for (int m = 0; m < C; m++) acc += convW[k * C + m] * trW[m * C + j];
    } else if (j < 2 * C) {
        int j2 = j - C;
        for (int m = 0; m < C; m++) acc += convW[C * C + k * C + m] * trW[C * C + m * C + j2];
    } else {
        int ja = j - 2 * C;
        for (int m = 0; m < C; m++)
            acc += 0.5f * (convW[k * C + m] + convW[C * C + k * C + m]) * attnW1[m * ATT_H + ja];
    }
    Wcat[(size_t)k * HCOLS + j] = acc;
}

// fused bias bcat [640]
__global__ __launch_bounds__(640)
void k_bcat(const float* __restrict__ convb, const float* __restrict__ trb,
            const float* __restrict__ trW, const float* __restrict__ attnW1,
            const float* __restrict__ attnb1, float* __restrict__ bcat) {
    int j = threadIdx.x;
    if (j >= HCOLS) return;
    float acc = 0.f;
    if (j < C) {
        for (int m = 0; m < C; m++) acc += convb[m] * trW[m * C + j];
        acc += trb[j];
    } else if (j < 2 * C) {
        int j2 = j - C;
        for (int m = 0; m < C; m++) acc += convb[C + m] * trW[C * C + m * C + j2];
        acc += trb[C + j2];
    } else {
        int ja = j - 2 * C;
        for (int m = 0; m < C; m++)
            acc += 0.5f * (convb[m] + convb[C + m]) * attnW1[m * ATT_H + ja];
        acc += attnb1[ja];
    }
    bcat[j] = acc;
}

// ---------------- K6: GEMM  ge[20000x640] = agg_e @ Wcat --------------------
#define BM 128
#define BN 64
#define BK 32
__global__ __launch_bounds__(256)
void k_gemm_e(const float* __restrict__ A, const float* __restrict__ Wcat,
              float* __restrict__ ge) {
    __shared__ float As[BK][BM + 4];
    __shared__ float Bs[BK][BN + 4];
    const int t = threadIdx.x;
    const int tx = t & 15, ty = t >> 4;
    const int by = blockIdx.x / 10;
    const int bx = blockIdx.x % 10;
    const int row0 = by * BM;
    const int col0 = bx * BN;

    float acc[8][4];
#pragma unroll
    for (int i = 0; i < 8; i++)
#pragma unroll
        for (int j = 0; j < 4; j++) acc[i][j] = 0.f;

    for (int kb = 0; kb < C; kb += BK) {
#pragma unroll
        for (int i = 0; i < 4; i++) {
            int f4 = t + i * 256;
            int k4 = f4 & 7;
            int r  = f4 >> 3;
            int row = row0 + r;
            float4 v = make_float4(0.f, 0.f, 0.f, 0.f);
            if (row < N_EDGES)
                v = *reinterpret_cast<const float4*>(A + (size_t)row * C + kb + k4 * 4);
            As[k4 * 4 + 0][r] = v.x;
            As[k4 * 4 + 1][r] = v.y;
            As[k4 * 4 + 2][r] = v.z;
            As[k4 * 4 + 3][r] = v.w;
        }
#pragma unroll
        for (int i = 0; i < 2; i++) {
            int f4 = t + i * 256;
            int c4 = f4 & 15;
            int kk = f4 >> 4;
            float4 v = *reinterpret_cast<const float4*>(
                Wcat + (size_t)(kb + kk) * HCOLS + col0 + c4 * 4);
            *reinterpret_cast<float4*>(&Bs[kk][c4 * 4]) = v;
        }
        __syncthreads();
#pragma unroll
        for (int kk = 0; kk < BK; ++kk) {
            float4 b4 = *reinterpret_cast<const float4*>(&Bs[kk][tx * 4]);
            float4 a0 = *reinterpret_cast<const float4*>(&As[kk][ty * 8]);
            float4 a1 = *reinterpret_cast<const float4*>(&As[kk][ty * 8 + 4]);
            float a[8] = {a0.x, a0.y, a0.z, a0.w, a1.x, a1.y, a1.z, a1.w};
            float b[4] = {b4.x, b4.y, b4.z, b4.w};
#pragma unroll
            for (int i = 0; i < 8; i++)
#pragma unroll
                for (int j = 0; j < 4; j++) acc[i][j] += a[i] * b[j];
        }
        __syncthreads();
    }
#pragma unroll
    for (int i = 0; i < 8; i++) {
        int row = row0 + ty * 8 + i;
        if (row < N_EDGES) {
            float4 o = make_float4(acc[i][0], acc[i][1], acc[i][2], acc[i][3]);
            *reinterpret_cast<float4*>(ge + (size_t)row * HCOLS + col0 + tx * 4) = o;
        }
    }
}

// ---------------- K7: fused node gather + epilogue + attn probs -------------
// one wave per node: h[n][0:512] = Dinv[n]*sum ge[e][0:512] + bcat[0:512]
// attn slice (cols 512:640) consumed in-register -> softmax -> dslots
__global__ __launch_bounds__(256)
void k_gather_h(const int* __restrict__ sorted_edge, const int* __restrict__ v_start,
                const float* __restrict__ ge, const float* __restrict__ Dinv,
                const float* __restrict__ bcat, const float* __restrict__ W2,
                const float* __restrict__ b2, float* __restrict__ h,
                float* __restrict__ dslots) {
    int n = blockIdx.x * 4 + (threadIdx.x >> 6);
    int lane = threadIdx.x & 63;
    float2 acc[5];
#pragma unroll
    for (int k = 0; k < 5; k++) acc[k] = make_float2(0.f, 0.f);

    int s = v_start[n], t = v_start[n + 1];
    for (int p = s; p < t; ++p) {
        int e = sorted_edge[p];
        const float2* gr = reinterpret_cast<const float2*>(ge + (size_t)e * HCOLS);
#pragma unroll
        for (int k = 0; k < 5; k++) {
            float2 v = gr[k * 64 + lane];
            acc[k].x += v.x; acc[k].y += v.y;
        }
    }
    float di = Dinv[n];
    const float2* bc = reinterpret_cast<const float2*>(bcat);
#pragma unroll
    for (int k = 0; k < 5; k++) {
        float2 b = bc[k * 64 + lane];
        acc[k].x = acc[k].x * di + b.x;
        acc[k].y = acc[k].y * di + b.y;
    }
    // store cols 0..511
    float2* hr = reinterpret_cast<float2*>(h + (size_t)n * HST);
#pragma unroll
    for (int k = 0; k < 4; k++) hr[k * 64 + lane] = acc[k];

    // attn: chunk 4 holds cols 512 + lane*2, +1  (m = lane*2)
    float r0 = fmaxf(acc[4].x, 0.f), r1 = fmaxf(acc[4].y, 0.f);
    int m = lane * 2;
    float L0 = r0 * W2[m * 2 + 0] + r1 * W2[m * 2 + 2];
    float L1 = r0 * W2[m * 2 + 1] + r1 * W2[m * 2 + 3];
#pragma unroll
    for (int off = 32; off; off >>= 1) {
        L0 += __shfl_down(L0, off);
        L1 += __shfl_down(L1, off);
    }
    __shared__ float red[4][2];
    int wave = threadIdx.x >> 6;
    if (lane == 0) {
        L0 += b2[0]; L1 += b2[1];
        float mx = fmaxf(L0, L1);
        float e0 = expf(L0 - mx), e1 = expf(L1 - mx);
        float inv = 1.f / (e0 + e1);
        red[wave][0] = e0 * inv;
        red[wave][1] = e1 * inv;
    }
    __syncthreads();
    if (threadIdx.x == 0) {
        int slot = (blockIdx.x & 63) * 2;
        atomicAdd(&dslots[slot + 0], red[0][0] + red[1][0] + red[2][0] + red[3][0]);
        atomicAdd(&dslots[slot + 1], red[0][1] + red[1][1] + red[2][1] + red[3][1]);
    }
}

// reduce 64 slot-pairs -> dsum[2]
__global__ __launch_bounds__(64)
void k_dsum(const float* __restrict__ dslots, float* __restrict__ dsum) {
    float p0 = dslots[threadIdx.x * 2 + 0];
    float p1 = dslots[threadIdx.x * 2 + 1];
#pragma unroll
    for (int off = 32; off; off >>= 1) {
        p0 += __shfl_down(p0, off);
        p1 += __shfl_down(p1, off);
    }
    if (threadIdx.x == 0) { dsum[0] = p0; dsum[1] = p1; }
}

// ---------------- K8: LayerNorm + ReLU + weighted combine -------------------
__global__ __launch_bounds__(256)
void k_final(const float* __restrict__ h, const float* __restrict__ ln_g,
             const float* __restrict__ ln_b, const float* __restrict__ sw,
             const float* __restrict__ dsum, float* __restrict__ out) {
    int r = blockIdx.x;
    int c = threadIdx.x;
    float h0 = h[(size_t)r * HST + c];
    float h1 = h[(size_t)r * HST + 256 + c];
    float s0 = h0, q0 = h0 * h0, s1 = h1, q1 = h1 * h1;
#pragma unroll
    for (int off = 32; off; off >>= 1) {
        s0 += __shfl_down(s0, off); q0 += __shfl_down(q0, off);
        s1 += __shfl_down(s1, off); q1 += __shfl_down(q1, off);
    }
    __shared__ float red[4][4];
    int wave = c >> 6, lane = c & 63;
    if (lane == 0) {
        red[wave][0] = s0; red[wave][1] = q0;
        red[wave][2] = s1; red[wave][3] = q1;
    }
    __syncthreads();
    s0 = red[0][0] + red[1][0] + red[2][0] + red[3][0];
    q0 = red[0][1] + red[1][1] + red[2][1] + red[3][1];
    s1 = red[0][2] + red[1][2] + red[2][2] + red[3][2];
    q1 = red[0][3] + red[1][3] + red[2][3] + red[3][3];
    const float invC = 1.f / 256.f;
    float mu0 = s0 * invC, mu1 = s1 * invC;
    float v0 = q0 * invC - mu0 * mu0;
    float v1 = q1 * invC - mu1 * mu1;
    float rs0 = rsqrtf(v0 + EPS), rs1 = rsqrtf(v1 + EPS);
    float t0 = fmaxf((h0 - mu0) * rs0 * ln_g[c] + ln_b[c], 0.f);
    float t1 = fmaxf((h1 - mu1) * rs1 * ln_g[256 + c] + ln_b[256 + c], 0.f);
    float a0 = sw[0], a1 = sw[1];
    float mx = fmaxf(a0, a1);
    float e0 = expf(a0 - mx), e1 = expf(a1 - mx);
    float inv = 1.f / (e0 + e1);
    float w0 = 0.5f * (e0 * inv + dsum[0] * (1.f / N_NODES));
    float w1 = 0.5f * (e1 * inv + dsum[1] * (1.f / N_NODES));
    out[(size_t)r * C + c] = w0 * t0 + w1 * t1;
}

// ---------------- launch ----------------
extern "C" void kernel_launch(void* const* d_in, const int* in_sizes, int n_in,
                              void* d_out, int out_size, void* d_ws, size_t ws_size,
                              hipStream_t stream) {
    const float* x       = (const float*)d_in[0];
    const int*   he      = (const int*)d_in[1];
    const int*   nidx    = he;
    const int*   eidx    = he + NNZ;
    const float* convW   = (const float*)d_in[2];
    const float* convb   = (const float*)d_in[3];
    const float* trW     = (const float*)d_in[4];
    const float* trb     = (const float*)d_in[5];
    const float* ln_g    = (const float*)d_in[6];
    const float* ln_b    = (const float*)d_in[7];
    const float* sw      = (const float*)d_in[8];
    const float* attnW1  = (const float*)d_in[9];
    const float* attnb1  = (const float*)d_in[10];
    const float* attnW2  = (const float*)d_in[11];
    const float* attnb2  = (const float*)d_in[12];
    float* out = (float*)d_out;

    // workspace layout
    float* ws     = (float*)d_ws;
    // --- zeroed region start ---
    float* dsum   = ws;                         // 8 f
    float* dslots = dsum + 8;                   // 128 f
    int*   deg_e  = (int*)(dslots + 128);       // 20000 i
    int*   deg_v  = deg_e + 20000;              // 100000 i
    int*   cur_e  = deg_v + 100000;             // 20000 i
    int*   cur_v  = cur_e + 20000;              // 100000 i
    // --- zeroed region end (240136 words) ---
    int*   e_start= cur_v + 100000;             // 20004 i
    int*   v_start= e_start + 20004;            // 100004 i
    int*   bsum_e = v_start + 100004;           // 64 i
    int*   bsum_v = bsum_e + 64;                // 128 i
    int*   s_node = bsum_v + 128;               // 640000 i
    int*   s_edge = s_node + 640000;            // 640000 i
    float* Wcat   = (float*)(s_edge + 640000);  // 163840 f
    float* bcat   = Wcat + 163840;              // 640 f
    float* Binv   = bcat + 640;                 // 20000 f
    float* Dinv   = Binv + 20000;               // 100000 f
    float* agg_e  = Dinv + 100000;              // 5,120,000 f
    float* ge     = agg_e + 5120000;            // 12,800,000 f
    float* h      = ge + 12800000;              // 51,200,000 f

    size_t zero_bytes = (size_t)(8 + 128 + 20000 + 100000 + 20000 + 100000) * 4;
    hipMemsetAsync(dsum, 0, zero_bytes, stream);

    k_degrees<<<(NNZ + 255) / 256, 256, 0, stream>>>(nidx, eidx, deg_e, deg_v);
    k_invert<<<(N_EDGES + 255) / 256, 256, 0, stream>>>(deg_e, Binv, N_EDGES);
    k_invert<<<(N_NODES + 255) / 256, 256, 0, stream>>>(deg_v, Dinv, N_NODES);

    int nbe = (N_EDGES + 1023) / 1024;   // 20
    int nbv = (N_NODES + 1023) / 1024;   // 98
    k_chunk_sums<<<nbe, 256, 0, stream>>>(deg_e, bsum_e, N_EDGES);
    k_scan_bsum<<<1, 128, 0, stream>>>(bsum_e, nbe, e_start, N_EDGES);
    k_scan_final<<<nbe, 1024, 0, stream>>>(deg_e, bsum_e, e_start, N_EDGES);
    k_chunk_sums<<<nbv, 256, 0, stream>>>(deg_v, bsum_v, N_NODES);
    k_scan_bsum<<<1, 128, 0, stream>>>(bsum_v, nbv, v_start, N_NODES);
    k_scan_final<<<nbv, 1024, 0, stream>>>(deg_v, bsum_v, v_start, N_NODES);

    k_fill<<<(NNZ + 255) / 256, 256, 0, stream>>>(nidx, eidx, e_start, v_start,
                                                  cur_e, cur_v, s_node, s_edge);

    k_wcat<<<(C * HCOLS + 255) / 256, 256, 0, stream>>>(convW, trW, attnW1, Wcat);
    k_bcat<<<1, 640, 0, stream>>>(convb, trb, trW, attnW1, attnb1, bcat);

    k_gather_e<<<N_EDGES / 4, 256, 0, stream>>>(s_node, e_start, x, Binv, agg_e);

    int row_blocks = (N_EDGES + BM - 1) / BM;   // 157
    k_gemm_e<<<row_blocks * 10, 256, 0, stream>>>(agg_e, Wcat, ge);

    k_gather_h<<<N_NODES / 4, 256, 0, stream>>>(s_edge, v_start, ge, Dinv, bcat,
                                                attnW2, attnb2, h, dslots);
    k_dsum<<<1, 64, 0, stream>>>(dslots, dsum);

    k_final<<<N_NODES, 256, 0, stream>>>(h, ln_g, ln_b, sw, dsum, out);
}

// Round 7
// 805.748 us; speedup vs baseline: 6.7180x; 1.1075x over previous
//
#include <hip/hip_runtime.h>
#include <math.h>

#define N_NODES 100000
#define N_EDGES 20000
#define NNZ     640000
#define C       256
#define ATT_H   128
#define HCOLS   640   // ge cols: 256 (h0) + 256 (h1) + 128 (a1)
#define EPS     1e-5f

typedef unsigned short ushort_t;
typedef unsigned int uint_t;

__device__ __forceinline__ ushort_t f2bf(float f) {
    union { float f; unsigned u; } v; v.f = f;
    unsigned r = v.u + 0x7FFFu + ((v.u >> 16) & 1u);  // RNE
    return (ushort_t)(r >> 16);
}
__device__ __forceinline__ float bfu(ushort_t h) {
    union { unsigned u; float f; } v; v.u = ((unsigned)h) << 16;
    return v.f;
}
__device__ __forceinline__ float bflo(uint_t u) {
    union { unsigned u; float f; } v; v.u = u << 16; return v.f;
}
__device__ __forceinline__ float bfhi(uint_t u) {
    union { unsigned u; float f; } v; v.u = u & 0xFFFF0000u; return v.f;
}

// ---------------- K1: integer degree histograms ----------------
__global__ __launch_bounds__(256)
void k_degrees(const int* __restrict__ nidx, const int* __restrict__ eidx,
               int* __restrict__ deg_e, int* __restrict__ deg_v) {
    int j = blockIdx.x * blockDim.x + threadIdx.x;
    if (j < NNZ) {
        atomicAdd(&deg_e[eidx[j]], 1);
        atomicAdd(&deg_v[nidx[j]], 1);
    }
}

__global__ __launch_bounds__(256)
void k_invert(const int* __restrict__ cnt, float* __restrict__ inv, int n) {
    int i = blockIdx.x * blockDim.x + threadIdx.x;
    if (i < n) { int d = cnt[i]; inv[i] = d > 0 ? 1.f / (float)d : 0.f; }
}

// ---------------- K2: 3-phase multi-block exclusive scan --------------------
__global__ __launch_bounds__(256)
void k_chunk_sums(const int* __restrict__ cnt, int* __restrict__ bsum, int n) {
    int base = blockIdx.x * 1024;
    int s = 0;
    for (int i = threadIdx.x; i < 1024; i += 256) {
        int g = base + i;
        s += (g < n) ? cnt[g] : 0;
    }
#pragma unroll
    for (int off = 32; off; off >>= 1) s += __shfl_down(s, off);
    __shared__ int red[4];
    int wave = threadIdx.x >> 6, lane = threadIdx.x & 63;
    if (lane == 0) red[wave] = s;
    __syncthreads();
    if (threadIdx.x == 0) bsum[blockIdx.x] = red[0] + red[1] + red[2] + red[3];
}

__global__ __launch_bounds__(128)
void k_scan_bsum(int* __restrict__ bsum, int nb, int* __restrict__ start, int n) {
    __shared__ int tmp[128];
    int v = (threadIdx.x < nb) ? bsum[threadIdx.x] : 0;
    tmp[threadIdx.x] = v;
    __syncthreads();
    for (int off = 1; off < 128; off <<= 1) {
        int a = (threadIdx.x >= off) ? tmp[threadIdx.x - off] : 0;
        __syncthreads();
        tmp[threadIdx.x] += a;
        __syncthreads();
    }
    if (threadIdx.x < nb) bsum[threadIdx.x] = tmp[threadIdx.x] - v;  // exclusive
    if (threadIdx.x == nb - 1) start[n] = tmp[threadIdx.x];          // total
}

__global__ __launch_bounds__(1024)
void k_scan_final(const int* __restrict__ cnt, const int* __restrict__ bsum,
                  int* __restrict__ start, int n) {
    __shared__ int tmp[1024];
    int i = blockIdx.x * 1024 + threadIdx.x;
    int v = (i < n) ? cnt[i] : 0;
    tmp[threadIdx.x] = v;
    __syncthreads();
    for (int off = 1; off < 1024; off <<= 1) {
        int a = (threadIdx.x >= off) ? tmp[threadIdx.x - off] : 0;
        __syncthreads();
        tmp[threadIdx.x] += a;
        __syncthreads();
    }
    if (i < n) start[i] = bsum[blockIdx.x] + tmp[threadIdx.x] - v;  // exclusive
}

// ---------------- K3: fill CSR adjacency ------------------------------------
__global__ __launch_bounds__(256)
void k_fill(const int* __restrict__ nidx, const int* __restrict__ eidx,
            const int* __restrict__ e_start, const int* __restrict__ v_start,
            int* __restrict__ cur_e, int* __restrict__ cur_v,
            int* __restrict__ sorted_node, int* __restrict__ sorted_edge) {
    int j = blockIdx.x * blockDim.x + threadIdx.x;
    if (j < NNZ) {
        int n = nidx[j], e = eidx[j];
        int pe = atomicAdd(&cur_e[e], 1);
        sorted_node[e_start[e] + pe] = n;
        int pv = atomicAdd(&cur_v[n], 1);
        sorted_edge[v_start[n] + pv] = e;
    }
}

// ---------------- K4: x -> bf16 copy ----------------------------------------
__global__ __launch_bounds__(256)
void k_xcast(const float4* __restrict__ x4, ushort4* __restrict__ xb4) {
    int i = blockIdx.x * blockDim.x + threadIdx.x;   // 6,400,000 float4s
    float4 v = x4[i];
    ushort4 o;
    o.x = f2bf(v.x); o.y = f2bf(v.y); o.z = f2bf(v.z); o.w = f2bf(v.w);
    xb4[i] = o;
}

// ---------------- K5: per-edge gather (bf16 x -> bf16 agg_e) ----------------
__global__ __launch_bounds__(256)
void k_gather_e(const int* __restrict__ sorted_node, const int* __restrict__ e_start,
                const ushort_t* __restrict__ xb, const float* __restrict__ Binv,
                ushort_t* __restrict__ agg_eb) {
    int e = blockIdx.x * 4 + (threadIdx.x >> 6);
    int lane = threadIdx.x & 63;
    int s = e_start[e], t = e_start[e + 1];
    float ax = 0.f, ay = 0.f, az = 0.f, aw = 0.f;
    for (int p = s; p < t; ++p) {
        int n = sorted_node[p];
        ushort4 v = *reinterpret_cast<const ushort4*>(xb + (size_t)n * C + lane * 4);
        ax += bfu(v.x); ay += bfu(v.y); az += bfu(v.z); aw += bfu(v.w);
    }
    float bi = Binv[e];
    ushort4 o;
    o.x = f2bf(ax * bi); o.y = f2bf(ay * bi); o.z = f2bf(az * bi); o.w = f2bf(aw * bi);
    *reinterpret_cast<ushort4*>(agg_eb + (size_t)e * C + lane * 4) = o;
}

// ---------------- K6: fused weight matrix Wcat [256][640] (f32) -------------
__global__ __launch_bounds__(256)
void k_wcat(const float* __restrict__ convW, const float* __restrict__ trW,
            const float* __restrict__ attnW1, float* __restrict__ Wcat) {
    int tid = blockIdx.x * blockDim.x + threadIdx.x;
    if (tid >= C * HCOLS) return;
    int k = tid / HCOLS, j = tid % HCOLS;
    float acc = 0.f;
    if (j < C) {
        for (int m = 0; m < C; m++) acc += convW[k * C + m] * trW[m * C + j];
    } else if (j < 2 * C) {
        int j2 = j - C;
        for (int m = 0; m < C; m++) acc += convW[C * C + k * C + m] * trW[C * C + m * C + j2];
    } else {
        int ja = j - 2 * C;
        for (int m = 0; m < C; m++)
            acc += 0.5f * (convW[k * C + m] + convW[C * C + k * C + m]) * attnW1[m * ATT_H + ja];
    }
    Wcat[(size_t)k * HCOLS + j] = acc;
}

__global__ __launch_bounds__(640)
void k_bcat(const float* __restrict__ convb, const float* __restrict__ trb,
            const float* __restrict__ trW, const float* __restrict__ attnW1,
            const float* __restrict__ attnb1, float* __restrict__ bcat) {
    int j = threadIdx.x;
    if (j >= HCOLS) return;
    float acc = 0.f;
    if (j < C) {
        for (int m = 0; m < C; m++) acc += convb[m] * trW[m * C + j];
        acc += trb[j];
    } else if (j < 2 * C) {
        int j2 = j - C;
        for (int m = 0; m < C; m++) acc += convb[C + m] * trW[C * C + m * C + j2];
        acc += trb[C + j2];
    } else {
        int ja = j - 2 * C;
        for (int m = 0; m < C; m++)
            acc += 0.5f * (convb[m] + convb[C + m]) * attnW1[m * ATT_H + ja];
        acc += attnb1[ja];
    }
    bcat[j] = acc;
}

// ---------------- K7: GEMM  ge[20000x640](bf16) = agg_e(bf16) @ Wcat(f32) ---
#define BM 128
#define BN 64
#define BK 32
__global__ __launch_bounds__(256)
void k_gemm_e(const ushort_t* __restrict__ Ab, const float* __restrict__ Wcat,
              ushort_t* __restrict__ geb) {
    __shared__ float As[BK][BM + 4];
    __shared__ float Bs[BK][BN + 4];
    const int t = threadIdx.x;
    const int tx = t & 15, ty = t >> 4;
    const int by = blockIdx.x / 10;
    const int bx = blockIdx.x % 10;
    const int row0 = by * BM;
    const int col0 = bx * BN;

    float acc[8][4];
#pragma unroll
    for (int i = 0; i < 8; i++)
#pragma unroll
        for (int j = 0; j < 4; j++) acc[i][j] = 0.f;

    for (int kb = 0; kb < C; kb += BK) {
        // A tile: 128x32 bf16 = 512 groups of 8; 2 per thread
#pragma unroll
        for (int i = 0; i < 2; i++) {
            int g = t + i * 256;
            int kg = g & 3;        // which 8-wide k group
            int r  = g >> 2;       // row in tile
            int row = row0 + r;
            uint4 raw = make_uint4(0u, 0u, 0u, 0u);
            if (row < N_EDGES)
                raw = *reinterpret_cast<const uint4*>(Ab + (size_t)row * C + kb + kg * 8);
            int k0 = kg * 8;
            As[k0 + 0][r] = bflo(raw.x); As[k0 + 1][r] = bfhi(raw.x);
            As[k0 + 2][r] = bflo(raw.y); As[k0 + 3][r] = bfhi(raw.y);
            As[k0 + 4][r] = bflo(raw.z); As[k0 + 5][r] = bfhi(raw.z);
            As[k0 + 6][r] = bflo(raw.w); As[k0 + 7][r] = bfhi(raw.w);
        }
#pragma unroll
        for (int i = 0; i < 2; i++) {
            int f4 = t + i * 256;
            int c4 = f4 & 15;
            int kk = f4 >> 4;
            float4 v = *reinterpret_cast<const float4*>(
                Wcat + (size_t)(kb + kk) * HCOLS + col0 + c4 * 4);
            *reinterpret_cast<float4*>(&Bs[kk][c4 * 4]) = v;
        }
        __syncthreads();
#pragma unroll
        for (int kk = 0; kk < BK; ++kk) {
            float4 b4 = *reinterpret_cast<const float4*>(&Bs[kk][tx * 4]);
            float4 a0 = *reinterpret_cast<const float4*>(&As[kk][ty * 8]);
            float4 a1 = *reinterpret_cast<const float4*>(&As[kk][ty * 8 + 4]);
            float a[8] = {a0.x, a0.y, a0.z, a0.w, a1.x, a1.y, a1.z, a1.w};
            float b[4] = {b4.x, b4.y, b4.z, b4.w};
#pragma unroll
            for (int i = 0; i < 8; i++)
#pragma unroll
                for (int j = 0; j < 4; j++) acc[i][j] += a[i] * b[j];
        }
        __syncthreads();
    }
#pragma unroll
    for (int i = 0; i < 8; i++) {
        int row = row0 + ty * 8 + i;
        if (row < N_EDGES) {
            ushort4 o;
            o.x = f2bf(acc[i][0]); o.y = f2bf(acc[i][1]);
            o.z = f2bf(acc[i][2]); o.w = f2bf(acc[i][3]);
            *reinterpret_cast<ushort4*>(geb + (size_t)row * HCOLS + col0 + tx * 4) = o;
        }
    }
}

// ---------------- K8 pass1: attn-slice gather -> dynamic weight slots -------
__global__ __launch_bounds__(256)
void k_attn(const int* __restrict__ sorted_edge, const int* __restrict__ v_start,
            const ushort_t* __restrict__ geb, const float* __restrict__ Dinv,
            const float* __restrict__ bcat, const float* __restrict__ W2,
            const float* __restrict__ b2, float* __restrict__ dslots) {
    int n = blockIdx.x * 4 + (threadIdx.x >> 6);
    int lane = threadIdx.x & 63;
    float a0 = 0.f, a1 = 0.f;
    int s = v_start[n], t = v_start[n + 1];
    for (int p = s; p < t; ++p) {
        int e = sorted_edge[p];
        uint_t raw = *reinterpret_cast<const uint_t*>(geb + (size_t)e * HCOLS + 512 + lane * 2);
        a0 += bflo(raw);
        a1 += bfhi(raw);
    }
    float di = Dinv[n];
    float r0 = fmaxf(a0 * di + bcat[512 + lane * 2 + 0], 0.f);
    float r1 = fmaxf(a1 * di + bcat[512 + lane * 2 + 1], 0.f);
    int m = lane * 2;
    float L0 = r0 * W2[m * 2 + 0] + r1 * W2[m * 2 + 2];
    float L1 = r0 * W2[m * 2 + 1] + r1 * W2[m * 2 + 3];
#pragma unroll
    for (int off = 32; off; off >>= 1) {
        L0 += __shfl_down(L0, off);
        L1 += __shfl_down(L1, off);
    }
    __shared__ float red[4][2];
    int wave = threadIdx.x >> 6;
    if (lane == 0) {
        L0 += b2[0]; L1 += b2[1];
        float mx = fmaxf(L0, L1);
        float e0 = expf(L0 - mx), e1 = expf(L1 - mx);
        float inv = 1.f / (e0 + e1);
        red[wave][0] = e0 * inv;
        red[wave][1] = e1 * inv;
    }
    __syncthreads();
    if (threadIdx.x == 0) {
        int slot = (blockIdx.x & 63) * 2;
        atomicAdd(&dslots[slot + 0], red[0][0] + red[1][0] + red[2][0] + red[3][0]);
        atomicAdd(&dslots[slot + 1], red[0][1] + red[1][1] + red[2][1] + red[3][1]);
    }
}

// reduce slots and finalize combine weights w = 0.5*(softmax(sw) + dyn_mean)
__global__ __launch_bounds__(64)
void k_dsum_final(const float* __restrict__ dslots, const float* __restrict__ sw,
                  float* __restrict__ dsum) {
    float p0 = dslots[threadIdx.x * 2 + 0];
    float p1 = dslots[threadIdx.x * 2 + 1];
#pragma unroll
    for (int off = 32; off; off >>= 1) {
        p0 += __shfl_down(p0, off);
        p1 += __shfl_down(p1, off);
    }
    if (threadIdx.x == 0) {
        float a0 = sw[0], a1 = sw[1];
        float mx = fmaxf(a0, a1);
        float e0 = expf(a0 - mx), e1 = expf(a1 - mx);
        float inv = 1.f / (e0 + e1);
        dsum[0] = 0.5f * (e0 * inv + p0 * (1.f / N_NODES));
        dsum[1] = 0.5f * (e1 * inv + p1 * (1.f / N_NODES));
    }
}

// ---------------- K9 pass2: main gather + LN + ReLU + combine -> out --------
__global__ __launch_bounds__(256)
void k_out(const int* __restrict__ sorted_edge, const int* __restrict__ v_start,
           const ushort_t* __restrict__ geb, const float* __restrict__ Dinv,
           const float* __restrict__ bcat, const float* __restrict__ ln_g,
           const float* __restrict__ ln_b, const float* __restrict__ dsum,
           float* __restrict__ out) {
    int n = blockIdx.x * 4 + (threadIdx.x >> 6);
    int lane = threadIdx.x & 63;
    float4 acc0 = make_float4(0.f, 0.f, 0.f, 0.f);
    float4 acc1 = make_float4(0.f, 0.f, 0.f, 0.f);
    int s = v_start[n], t = v_start[n + 1];
    for (int p = s; p < t; ++p) {
        int e = sorted_edge[p];
        const ushort_t* base = geb + (size_t)e * HCOLS;
        uint2 ra = *reinterpret_cast<const uint2*>(base + lane * 4);
        uint2 rb = *reinterpret_cast<const uint2*>(base + 256 + lane * 4);
        acc0.x += bflo(ra.x); acc0.y += bfhi(ra.x);
        acc0.z += bflo(ra.y); acc0.w += bfhi(ra.y);
        acc1.x += bflo(rb.x); acc1.y += bfhi(rb.x);
        acc1.z += bflo(rb.y); acc1.w += bfhi(rb.y);
    }
    float di = Dinv[n];
    float4 b0 = *reinterpret_cast<const float4*>(bcat + lane * 4);
    float4 b1 = *reinterpret_cast<const float4*>(bcat + 256 + lane * 4);
    float4 h0, h1;
    h0.x = acc0.x * di + b0.x; h0.y = acc0.y * di + b0.y;
    h0.z = acc0.z * di + b0.z; h0.w = acc0.w * di + b0.w;
    h1.x = acc1.x * di + b1.x; h1.y = acc1.y * di + b1.y;
    h1.z = acc1.z * di + b1.z; h1.w = acc1.w * di + b1.w;

    float s0 = h0.x + h0.y + h0.z + h0.w;
    float q0 = h0.x * h0.x + h0.y * h0.y + h0.z * h0.z + h0.w * h0.w;
    float s1 = h1.x + h1.y + h1.z + h1.w;
    float q1 = h1.x * h1.x + h1.y * h1.y + h1.z * h1.z + h1.w * h1.w;
#pragma unroll
    for (int off = 32; off; off >>= 1) {
        s0 += __shfl_xor(s0, off); q0 += __shfl_xor(q0, off);
        s1 += __shfl_xor(s1, off); q1 += __shfl_xor(q1, off);
    }
    const float invC = 1.f / 256.f;
    float mu0 = s0 * invC, mu1 = s1 * invC;
    float v0 = q0 * invC - mu0 * mu0;
    float v1 = q1 * invC - mu1 * mu1;
    float rs0 = rsqrtf(v0 + EPS), rs1 = rsqrtf(v1 + EPS);

    float4 g0 = *reinterpret_cast<const float4*>(ln_g + lane * 4);
    float4 gb0 = *reinterpret_cast<const float4*>(ln_b + lane * 4);
    float4 g1 = *reinterpret_cast<const float4*>(ln_g + 256 + lane * 4);
    float4 gb1 = *reinterpret_cast<const float4*>(ln_b + 256 + lane * 4);
    float w0 = dsum[0], w1 = dsum[1];

    float4 o;
    o.x = w0 * fmaxf((h0.x - mu0) * rs0 * g0.x + gb0.x, 0.f)
        + w1 * fmaxf((h1.x - mu1) * rs1 * g1.x + gb1.x, 0.f);
    o.y = w0 * fmaxf((h0.y - mu0) * rs0 * g0.y + gb0.y, 0.f)
        + w1 * fmaxf((h1.y - mu1) * rs1 * g1.y + gb1.y, 0.f);
    o.z = w0 * fmaxf((h0.z - mu0) * rs0 * g0.z + gb0.z, 0.f)
        + w1 * fmaxf((h1.z - mu1) * rs1 * g1.z + gb1.z, 0.f);
    o.w = w0 * fmaxf((h0.w - mu0) * rs0 * g0.w + gb0.w, 0.f)
        + w1 * fmaxf((h1.w - mu1) * rs1 * g1.w + gb1.w, 0.f);
    *reinterpret_cast<float4*>(out + (size_t)n * C + lane * 4) = o;
}

// ---------------- launch ----------------
extern "C" void kernel_launch(void* const* d_in, const int* in_sizes, int n_in,
                              void* d_out, int out_size, void* d_ws, size_t ws_size,
                              hipStream_t stream) {
    const float* x       = (const float*)d_in[0];
    const int*   he      = (const int*)d_in[1];
    const int*   nidx    = he;
    const int*   eidx    = he + NNZ;
    const float* convW   = (const float*)d_in[2];
    const float* convb   = (const float*)d_in[3];
    const float* trW     = (const float*)d_in[4];
    const float* trb     = (const float*)d_in[5];
    const float* ln_g    = (const float*)d_in[6];
    const float* ln_b    = (const float*)d_in[7];
    const float* sw      = (const float*)d_in[8];
    const float* attnW1  = (const float*)d_in[9];
    const float* attnb1  = (const float*)d_in[10];
    const float* attnW2  = (const float*)d_in[11];
    const float* attnb2  = (const float*)d_in[12];
    float* out = (float*)d_out;

    // workspace layout
    float* ws     = (float*)d_ws;
    // --- zeroed region start ---
    float* dsum   = ws;                         // 8 f
    float* dslots = dsum + 8;                   // 128 f
    int*   deg_e  = (int*)(dslots + 128);       // 20000 i
    int*   deg_v  = deg_e + 20000;              // 100000 i
    int*   cur_e  = deg_v + 100000;             // 20000 i
    int*   cur_v  = cur_e + 20000;              // 100000 i
    // --- zeroed region end (240136 words) ---
    int*   e_start= cur_v + 100000;             // 20004 i
    int*   v_start= e_start + 20004;            // 100004 i
    int*   bsum_e = v_start + 100004;           // 64 i
    int*   bsum_v = bsum_e + 64;                // 128 i
    int*   s_node = bsum_v + 128;               // 640000 i
    int*   s_edge = s_node + 640000;            // 640000 i
    float* Wcat   = (float*)(s_edge + 640000);  // 163840 f
    float* bcat   = Wcat + 163840;              // 640 f
    float* Binv   = bcat + 640;                 // 20000 f
    float* Dinv   = Binv + 20000;               // 100000 f
    ushort_t* xb     = (ushort_t*)(Dinv + 100000);  // 25,600,000 us (16B-aligned)
    ushort_t* agg_eb = xb + 25600000;               // 5,120,000 us
    ushort_t* geb    = agg_eb + 5120000;            // 12,800,000 us

    size_t zero_bytes = (size_t)(8 + 128 + 20000 + 100000 + 20000 + 100000) * 4;
    hipMemsetAsync(dsum, 0, zero_bytes, stream);

    k_degrees<<<(NNZ + 255) / 256, 256, 0, stream>>>(nidx, eidx, deg_e, deg_v);
    k_invert<<<(N_EDGES + 255) / 256, 256, 0, stream>>>(deg_e, Binv, N_EDGES);
    k_invert<<<(N_NODES + 255) / 256, 256, 0, stream>>>(deg_v, Dinv, N_NODES);

    int nbe = (N_EDGES + 1023) / 1024;   // 20
    int nbv = (N_NODES + 1023) / 1024;   // 98
    k_chunk_sums<<<nbe, 256, 0, stream>>>(deg_e, bsum_e, N_EDGES);
    k_scan_bsum<<<1, 128, 0, stream>>>(bsum_e, nbe, e_start, N_EDGES);
    k_scan_final<<<nbe, 1024, 0, stream>>>(deg_e, bsum_e, e_start, N_EDGES);
    k_chunk_sums<<<nbv, 256, 0, stream>>>(deg_v, bsum_v, N_NODES);
    k_scan_bsum<<<1, 128, 0, stream>>>(bsum_v, nbv, v_start, N_NODES);
    k_scan_final<<<nbv, 1024, 0, stream>>>(deg_v, bsum_v, v_start, N_NODES);

    k_fill<<<(NNZ + 255) / 256, 256, 0, stream>>>(nidx, eidx, e_start, v_start,
                                                  cur_e, cur_v, s_node, s_edge);

    k_wcat<<<(C * HCOLS + 255) / 256, 256, 0, stream>>>(convW, trW, attnW1, Wcat);
    k_bcat<<<1, 640, 0, stream>>>(convb, trb, trW, attnW1, attnb1, bcat);

    k_xcast<<<25000, 256, 0, stream>>>((const float4*)x, (ushort4*)xb);

    k_gather_e<<<N_EDGES / 4, 256, 0, stream>>>(s_node, e_start, xb, Binv, agg_eb);

    int row_blocks = (N_EDGES + BM - 1) / BM;   // 157
    k_gemm_e<<<row_blocks * 10, 256, 0, stream>>>(agg_eb, Wcat, geb);

    k_attn<<<N_NODES / 4, 256, 0, stream>>>(s_edge, v_start, geb, Dinv, bcat,
                                            attnW2, attnb2, dslots);
    k_dsum_final<<<1, 64, 0, stream>>>(dslots, sw, dsum);

    k_out<<<N_NODES / 4, 256, 0, stream>>>(s_edge, v_start, geb, Dinv, bcat,
                                           ln_g, ln_b, dsum, out);
}

// Round 8
// 780.263 us; speedup vs baseline: 6.9374x; 1.0327x over previous
//
#include <hip/hip_runtime.h>
#include <math.h>

#define N_NODES 100000
#define N_EDGES 20000
#define NNZ     640000
#define C       256
#define ATT_H   128
#define HCOLS   640   // ge cols: 256 (h0) + 256 (h1) + 128 (a1)
#define EPS     1e-5f

typedef unsigned short ushort_t;
typedef unsigned int uint_t;

__device__ __forceinline__ ushort_t f2bf(float f) {
    union { float f; unsigned u; } v; v.f = f;
    unsigned r = v.u + 0x7FFFu + ((v.u >> 16) & 1u);  // RNE
    return (ushort_t)(r >> 16);
}
__device__ __forceinline__ float bfu(ushort_t h) {
    union { unsigned u; float f; } v; v.u = ((unsigned)h) << 16;
    return v.f;
}
__device__ __forceinline__ float bflo(uint_t u) {
    union { unsigned u; float f; } v; v.u = u << 16; return v.f;
}
__device__ __forceinline__ float bfhi(uint_t u) {
    union { unsigned u; float f; } v; v.u = u & 0xFFFF0000u; return v.f;
}
__device__ __forceinline__ uint_t pack2(float lo, float hi) {
    return (uint_t)f2bf(lo) | ((uint_t)f2bf(hi) << 16);
}

// ---------------- K1: integer degree histograms ----------------
__global__ __launch_bounds__(256)
void k_degrees(const int* __restrict__ nidx, const int* __restrict__ eidx,
               int* __restrict__ deg_e, int* __restrict__ deg_v) {
    int j = blockIdx.x * blockDim.x + threadIdx.x;
    if (j < NNZ) {
        atomicAdd(&deg_e[eidx[j]], 1);
        atomicAdd(&deg_v[nidx[j]], 1);
    }
}

__global__ __launch_bounds__(256)
void k_invert(const int* __restrict__ cnt, float* __restrict__ inv, int n) {
    int i = blockIdx.x * blockDim.x + threadIdx.x;
    if (i < n) { int d = cnt[i]; inv[i] = d > 0 ? 1.f / (float)d : 0.f; }
}

// ---------------- K2: 3-phase multi-block exclusive scan --------------------
__global__ __launch_bounds__(256)
void k_chunk_sums(const int* __restrict__ cnt, int* __restrict__ bsum, int n) {
    int base = blockIdx.x * 1024;
    int s = 0;
    for (int i = threadIdx.x; i < 1024; i += 256) {
        int g = base + i;
        s += (g < n) ? cnt[g] : 0;
    }
#pragma unroll
    for (int off = 32; off; off >>= 1) s += __shfl_down(s, off);
    __shared__ int red[4];
    int wave = threadIdx.x >> 6, lane = threadIdx.x & 63;
    if (lane == 0) red[wave] = s;
    __syncthreads();
    if (threadIdx.x == 0) bsum[blockIdx.x] = red[0] + red[1] + red[2] + red[3];
}

__global__ __launch_bounds__(128)
void k_scan_bsum(int* __restrict__ bsum, int nb, int* __restrict__ start, int n) {
    __shared__ int tmp[128];
    int v = (threadIdx.x < nb) ? bsum[threadIdx.x] : 0;
    tmp[threadIdx.x] = v;
    __syncthreads();
    for (int off = 1; off < 128; off <<= 1) {
        int a = (threadIdx.x >= off) ? tmp[threadIdx.x - off] : 0;
        __syncthreads();
        tmp[threadIdx.x] += a;
        __syncthreads();
    }
    if (threadIdx.x < nb) bsum[threadIdx.x] = tmp[threadIdx.x] - v;  // exclusive
    if (threadIdx.x == nb - 1) start[n] = tmp[threadIdx.x];          // total
}

__global__ __launch_bounds__(1024)
void k_scan_final(const int* __restrict__ cnt, const int* __restrict__ bsum,
                  int* __restrict__ start, int n) {
    __shared__ int tmp[1024];
    int i = blockIdx.x * 1024 + threadIdx.x;
    int v = (i < n) ? cnt[i] : 0;
    tmp[threadIdx.x] = v;
    __syncthreads();
    for (int off = 1; off < 1024; off <<= 1) {
        int a = (threadIdx.x >= off) ? tmp[threadIdx.x - off] : 0;
        __syncthreads();
        tmp[threadIdx.x] += a;
        __syncthreads();
    }
    if (i < n) start[i] = bsum[blockIdx.x] + tmp[threadIdx.x] - v;  // exclusive
}

// ---------------- K3: fill CSR adjacency ------------------------------------
__global__ __launch_bounds__(256)
void k_fill(const int* __restrict__ nidx, const int* __restrict__ eidx,
            const int* __restrict__ e_start, const int* __restrict__ v_start,
            int* __restrict__ cur_e, int* __restrict__ cur_v,
            int* __restrict__ sorted_node, int* __restrict__ sorted_edge) {
    int j = blockIdx.x * blockDim.x + threadIdx.x;
    if (j < NNZ) {
        int n = nidx[j], e = eidx[j];
        int pe = atomicAdd(&cur_e[e], 1);
        sorted_node[e_start[e] + pe] = n;
        int pv = atomicAdd(&cur_v[n], 1);
        sorted_edge[v_start[n] + pv] = e;
    }
}

// ---------------- K4: x -> bf16 copy ----------------------------------------
__global__ __launch_bounds__(256)
void k_xcast(const float4* __restrict__ x4, ushort4* __restrict__ xb4) {
    int i = blockIdx.x * blockDim.x + threadIdx.x;   // 6,400,000 float4s
    float4 v = x4[i];
    ushort4 o;
    o.x = f2bf(v.x); o.y = f2bf(v.y); o.z = f2bf(v.z); o.w = f2bf(v.w);
    xb4[i] = o;
}

// ---------------- K5: per-edge gather (bf16 x -> bf16 agg_e) ----------------
// wave handles 2 edges: lanes 0-31 -> edge0, lanes 32-63 -> edge1
// lane covers cols (lane&31)*8 .. +7 via one uint4 (16B) per member
__global__ __launch_bounds__(256)
void k_gather_e(const int* __restrict__ sorted_node, const int* __restrict__ e_start,
                const ushort_t* __restrict__ xb, const float* __restrict__ Binv,
                ushort_t* __restrict__ agg_eb) {
    int wv = threadIdx.x >> 6;
    int lane = threadIdx.x & 63;
    int half = lane >> 5;
    int cl = lane & 31;
    int e = blockIdx.x * 8 + wv * 2 + half;
    int s = e_start[e], t = e_start[e + 1];
    float acc[8];
#pragma unroll
    for (int j = 0; j < 8; j++) acc[j] = 0.f;
    for (int p = s; p < t; ++p) {
        int n = sorted_node[p];
        uint4 raw = *reinterpret_cast<const uint4*>(xb + (size_t)n * C + cl * 8);
        acc[0] += bflo(raw.x); acc[1] += bfhi(raw.x);
        acc[2] += bflo(raw.y); acc[3] += bfhi(raw.y);
        acc[4] += bflo(raw.z); acc[5] += bfhi(raw.z);
        acc[6] += bflo(raw.w); acc[7] += bfhi(raw.w);
    }
    float bi = Binv[e];
    uint4 o;
    o.x = pack2(acc[0] * bi, acc[1] * bi);
    o.y = pack2(acc[2] * bi, acc[3] * bi);
    o.z = pack2(acc[4] * bi, acc[5] * bi);
    o.w = pack2(acc[6] * bi, acc[7] * bi);
    *reinterpret_cast<uint4*>(agg_eb + (size_t)e * C + cl * 8) = o;
}

// ---------------- K6: fused weight matrix Wcat [256][640] (f32) -------------
__global__ __launch_bounds__(256)
void k_wcat(const float* __restrict__ convW, const float* __restrict__ trW,
            const float* __restrict__ attnW1, float* __restrict__ Wcat) {
    int tid = blockIdx.x * blockDim.x + threadIdx.x;
    if (tid >= C * HCOLS) return;
    int k = tid / HCOLS, j = tid % HCOLS;
    float acc = 0.f;
    if (j < C) {
        for (int m = 0; m < C; m++) acc += convW[k * C + m] * trW[m * C + j];
    } else if (j < 2 * C) {
        int j2 = j - C;
        for (int m = 0; m < C; m++) acc += convW[C * C + k * C + m] * trW[C * C + m * C + j2];
    } else {
        int ja = j - 2 * C;
        for (int m = 0; m < C; m++)
            acc += 0.5f * (convW[k * C + m] + convW[C * C + k * C + m]) * attnW1[m * ATT_H + ja];
    }
    Wcat[(size_t)k * HCOLS + j] = acc;
}

__global__ __launch_bounds__(640)
void k_bcat(const float* __restrict__ convb, const float* __restrict__ trb,
            const float* __restrict__ trW, const float* __restrict__ attnW1,
            const float* __restrict__ attnb1, float* __restrict__ bcat) {
    int j = threadIdx.x;
    if (j >= HCOLS) return;
    float acc = 0.f;
    if (j < C) {
        for (int m = 0; m < C; m++) acc += convb[m] * trW[m * C + j];
        acc += trb[j];
    } else if (j < 2 * C) {
        int j2 = j - C;
        for (int m = 0; m < C; m++) acc += convb[C + m] * trW[C * C + m * C + j2];
        acc += trb[C + j2];
    } else {
        int ja = j - 2 * C;
        for (int m = 0; m < C; m++)
            acc += 0.5f * (convb[m] + convb[C + m]) * attnW1[m * ATT_H + ja];
        acc += attnb1[ja];
    }
    bcat[j] = acc;
}

// ---------------- K7: GEMM  ge[20000x640](bf16) = agg_e(bf16) @ Wcat(f32) ---
#define BM 128
#define BN 64
#define BK 32
__global__ __launch_bounds__(256)
void k_gemm_e(const ushort_t* __restrict__ Ab, const float* __restrict__ Wcat,
              ushort_t* __restrict__ geb) {
    __shared__ float As[BK][BM + 4];
    __shared__ float Bs[BK][BN + 4];
    const int t = threadIdx.x;
    const int tx = t & 15, ty = t >> 4;
    const int by = blockIdx.x / 10;
    const int bx = blockIdx.x % 10;
    const int row0 = by * BM;
    const int col0 = bx * BN;

    float acc[8][4];
#pragma unroll
    for (int i = 0; i < 8; i++)
#pragma unroll
        for (int j = 0; j < 4; j++) acc[i][j] = 0.f;

    for (int kb = 0; kb < C; kb += BK) {
#pragma unroll
        for (int i = 0; i < 2; i++) {
            int g = t + i * 256;
            int kg = g & 3;
            int r  = g >> 2;
            int row = row0 + r;
            uint4 raw = make_uint4(0u, 0u, 0u, 0u);
            if (row < N_EDGES)
                raw = *reinterpret_cast<const uint4*>(Ab + (size_t)row * C + kb + kg * 8);
            int k0 = kg * 8;
            As[k0 + 0][r] = bflo(raw.x); As[k0 + 1][r] = bfhi(raw.x);
            As[k0 + 2][r] = bflo(raw.y); As[k0 + 3][r] = bfhi(raw.y);
            As[k0 + 4][r] = bflo(raw.z); As[k0 + 5][r] = bfhi(raw.z);
            As[k0 + 6][r] = bflo(raw.w); As[k0 + 7][r] = bfhi(raw.w);
        }
#pragma unroll
        for (int i = 0; i < 2; i++) {
            int f4 = t + i * 256;
            int c4 = f4 & 15;
            int kk = f4 >> 4;
            float4 v = *reinterpret_cast<const float4*>(
                Wcat + (size_t)(kb + kk) * HCOLS + col0 + c4 * 4);
            *reinterpret_cast<float4*>(&Bs[kk][c4 * 4]) = v;
        }
        __syncthreads();
#pragma unroll
        for (int kk = 0; kk < BK; ++kk) {
            float4 b4 = *reinterpret_cast<const float4*>(&Bs[kk][tx * 4]);
            float4 a0 = *reinterpret_cast<const float4*>(&As[kk][ty * 8]);
            float4 a1 = *reinterpret_cast<const float4*>(&As[kk][ty * 8 + 4]);
            float a[8] = {a0.x, a0.y, a0.z, a0.w, a1.x, a1.y, a1.z, a1.w};
            float b[4] = {b4.x, b4.y, b4.z, b4.w};
#pragma unroll
            for (int i = 0; i < 8; i++)
#pragma unroll
                for (int j = 0; j < 4; j++) acc[i][j] += a[i] * b[j];
        }
        __syncthreads();
    }
#pragma unroll
    for (int i = 0; i < 8; i++) {
        int row = row0 + ty * 8 + i;
        if (row < N_EDGES) {
            ushort4 o;
            o.x = f2bf(acc[i][0]); o.y = f2bf(acc[i][1]);
            o.z = f2bf(acc[i][2]); o.w = f2bf(acc[i][3]);
            *reinterpret_cast<ushort4*>(geb + (size_t)row * HCOLS + col0 + tx * 4) = o;
        }
    }
}

// ---------------- K8 pass1: attn-slice gather -> dynamic weight slots -------
// wave per node; edges processed 4 at a time:
// lane = sub(2b) x colgroup(4b): sub = lane>>4 picks edge, cl = lane&15 picks 8 cols
__global__ __launch_bounds__(256)
void k_attn(const int* __restrict__ sorted_edge, const int* __restrict__ v_start,
            const ushort_t* __restrict__ geb, const float* __restrict__ Dinv,
            const float* __restrict__ bcat, const float* __restrict__ W2,
            const float* __restrict__ b2, float* __restrict__ dslots) {
    int n = blockIdx.x * 4 + (threadIdx.x >> 6);
    int lane = threadIdx.x & 63;
    int sub = lane >> 4;
    int cl  = lane & 15;
    float acc[8];
#pragma unroll
    for (int j = 0; j < 8; j++) acc[j] = 0.f;
    int s = v_start[n], t = v_start[n + 1];
    for (int p = s; p < t; p += 4) {
        int idx = p + sub;
        if (idx < t) {
            int e = sorted_edge[idx];
            uint4 raw = *reinterpret_cast<const uint4*>(geb + (size_t)e * HCOLS + 512 + cl * 8);
            acc[0] += bflo(raw.x); acc[1] += bfhi(raw.x);
            acc[2] += bflo(raw.y); acc[3] += bfhi(raw.y);
            acc[4] += bflo(raw.z); acc[5] += bfhi(raw.z);
            acc[6] += bflo(raw.w); acc[7] += bfhi(raw.w);
        }
    }
    // sum the 4 edge-subgroups (lane^16, lane^32 keep cl fixed)
#pragma unroll
    for (int j = 0; j < 8; j++) {
        acc[j] += __shfl_xor(acc[j], 16);
        acc[j] += __shfl_xor(acc[j], 32);
    }
    float di = Dinv[n];
    float L0 = 0.f, L1 = 0.f;
#pragma unroll
    for (int j = 0; j < 8; j++) {
        int c = cl * 8 + j;
        float r = fmaxf(acc[j] * di + bcat[512 + c], 0.f);
        L0 += r * W2[c * 2 + 0];
        L1 += r * W2[c * 2 + 1];
    }
    // reduce over the 16 col-groups
#pragma unroll
    for (int off = 8; off; off >>= 1) {
        L0 += __shfl_xor(L0, off);
        L1 += __shfl_xor(L1, off);
    }
    __shared__ float red[4][2];
    int wave = threadIdx.x >> 6;
    if (lane == 0) {
        L0 += b2[0]; L1 += b2[1];
        float mx = fmaxf(L0, L1);
        float e0 = expf(L0 - mx), e1 = expf(L1 - mx);
        float inv = 1.f / (e0 + e1);
        red[wave][0] = e0 * inv;
        red[wave][1] = e1 * inv;
    }
    __syncthreads();
    if (threadIdx.x == 0) {
        int slot = (blockIdx.x & 63) * 2;
        atomicAdd(&dslots[slot + 0], red[0][0] + red[1][0] + red[2][0] + red[3][0]);
        atomicAdd(&dslots[slot + 1], red[0][1] + red[1][1] + red[2][1] + red[3][1]);
    }
}

// reduce slots and finalize combine weights w = 0.5*(softmax(sw) + dyn_mean)
__global__ __launch_bounds__(64)
void k_dsum_final(const float* __restrict__ dslots, const float* __restrict__ sw,
                  float* __restrict__ dsum) {
    float p0 = dslots[threadIdx.x * 2 + 0];
    float p1 = dslots[threadIdx.x * 2 + 1];
#pragma unroll
    for (int off = 32; off; off >>= 1) {
        p0 += __shfl_down(p0, off);
        p1 += __shfl_down(p1, off);
    }
    if (threadIdx.x == 0) {
        float a0 = sw[0], a1 = sw[1];
        float mx = fmaxf(a0, a1);
        float e0 = expf(a0 - mx), e1 = expf(a1 - mx);
        float inv = 1.f / (e0 + e1);
        dsum[0] = 0.5f * (e0 * inv + p0 * (1.f / N_NODES));
        dsum[1] = 0.5f * (e1 * inv + p1 * (1.f / N_NODES));
    }
}

// ---------------- K9 pass2: main gather + LN + ReLU + combine -> out --------
__global__ __launch_bounds__(256)
void k_out(const int* __restrict__ sorted_edge, const int* __restrict__ v_start,
           const ushort_t* __restrict__ geb, const float* __restrict__ Dinv,
           const float* __restrict__ bcat, const float* __restrict__ ln_g,
           const float* __restrict__ ln_b, const float* __restrict__ dsum,
           float* __restrict__ out) {
    int n = blockIdx.x * 4 + (threadIdx.x >> 6);
    int lane = threadIdx.x & 63;
    float4 acc0 = make_float4(0.f, 0.f, 0.f, 0.f);
    float4 acc1 = make_float4(0.f, 0.f, 0.f, 0.f);
    int s = v_start[n], t = v_start[n + 1];
    for (int p = s; p < t; ++p) {
        int e = sorted_edge[p];
        const ushort_t* base = geb + (size_t)e * HCOLS;
        uint2 ra = *reinterpret_cast<const uint2*>(base + lane * 4);
        uint2 rb = *reinterpret_cast<const uint2*>(base + 256 + lane * 4);
        acc0.x += bflo(ra.x); acc0.y += bfhi(ra.x);
        acc0.z += bflo(ra.y); acc0.w += bfhi(ra.y);
        acc1.x += bflo(rb.x); acc1.y += bfhi(rb.x);
        acc1.z += bflo(rb.y); acc1.w += bfhi(rb.y);
    }
    float di = Dinv[n];
    float4 b0 = *reinterpret_cast<const float4*>(bcat + lane * 4);
    float4 b1 = *reinterpret_cast<const float4*>(bcat + 256 + lane * 4);
    float4 h0, h1;
    h0.x = acc0.x * di + b0.x; h0.y = acc0.y * di + b0.y;
    h0.z = acc0.z * di + b0.z; h0.w = acc0.w * di + b0.w;
    h1.x = acc1.x * di + b1.x; h1.y = acc1.y * di + b1.y;
    h1.z = acc1.z * di + b1.z; h1.w = acc1.w * di + b1.w;

    float s0 = h0.x + h0.y + h0.z + h0.w;
    float q0 = h0.x * h0.x + h0.y * h0.y + h0.z * h0.z + h0.w * h0.w;
    float s1 = h1.x + h1.y + h1.z + h1.w;
    float q1 = h1.x * h1.x + h1.y * h1.y + h1.z * h1.z + h1.w * h1.w;
#pragma unroll
    for (int off = 32; off; off >>= 1) {
        s0 += __shfl_xor(s0, off); q0 += __shfl_xor(q0, off);
        s1 += __shfl_xor(s1, off); q1 += __shfl_xor(q1, off);
    }
    const float invC = 1.f / 256.f;
    float mu0 = s0 * invC, mu1 = s1 * invC;
    float v0 = q0 * invC - mu0 * mu0;
    float v1 = q1 * invC - mu1 * mu1;
    float rs0 = rsqrtf(v0 + EPS), rs1 = rsqrtf(v1 + EPS);

    float4 g0 = *reinterpret_cast<const float4*>(ln_g + lane * 4);
    float4 gb0 = *reinterpret_cast<const float4*>(ln_b + lane * 4);
    float4 g1 = *reinterpret_cast<const float4*>(ln_g + 256 + lane * 4);
    float4 gb1 = *reinterpret_cast<const float4*>(ln_b + 256 + lane * 4);
    float w0 = dsum[0], w1 = dsum[1];

    float4 o;
    o.x = w0 * fmaxf((h0.x - mu0) * rs0 * g0.x + gb0.x, 0.f)
        + w1 * fmaxf((h1.x - mu1) * rs1 * g1.x + gb1.x, 0.f);
    o.y = w0 * fmaxf((h0.y - mu0) * rs0 * g0.y + gb0.y, 0.f)
        + w1 * fmaxf((h1.y - mu1) * rs1 * g1.y + gb1.y, 0.f);
    o.z = w0 * fmaxf((h0.z - mu0) * rs0 * g0.z + gb0.z, 0.f)
        + w1 * fmaxf((h1.z - mu1) * rs1 * g1.z + gb1.z, 0.f);
    o.w = w0 * fmaxf((h0.w - mu0) * rs0 * g0.w + gb0.w, 0.f)
        + w1 * fmaxf((h1.w - mu1) * rs1 * g1.w + gb1.w, 0.f);
    *reinterpret_cast<float4*>(out + (size_t)n * C + lane * 4) = o;
}

// ---------------- launch ----------------
extern "C" void kernel_launch(void* const* d_in, const int* in_sizes, int n_in,
                              void* d_out, int out_size, void* d_ws, size_t ws_size,
                              hipStream_t stream) {
    const float* x       = (const float*)d_in[0];
    const int*   he      = (const int*)d_in[1];
    const int*   nidx    = he;
    const int*   eidx    = he + NNZ;
    const float* convW   = (const float*)d_in[2];
    const float* convb   = (const float*)d_in[3];
    const float* trW     = (const float*)d_in[4];
    const float* trb     = (const float*)d_in[5];
    const float* ln_g    = (const float*)d_in[6];
    const float* ln_b    = (const float*)d_in[7];
    const float* sw      = (const float*)d_in[8];
    const float* attnW1  = (const float*)d_in[9];
    const float* attnb1  = (const float*)d_in[10];
    const float* attnW2  = (const float*)d_in[11];
    const float* attnb2  = (const float*)d_in[12];
    float* out = (float*)d_out;

    // workspace layout
    float* ws     = (float*)d_ws;
    // --- zeroed region start ---
    float* dsum   = ws;                         // 8 f
    float* dslots = dsum + 8;                   // 128 f
    int*   deg_e  = (int*)(dslots + 128);       // 20000 i
    int*   deg_v  = deg_e + 20000;              // 100000 i
    int*   cur_e  = deg_v + 100000;             // 20000 i
    int*   cur_v  = cur_e + 20000;              // 100000 i
    // --- zeroed region end (240136 words) ---
    int*   e_start= cur_v + 100000;             // 20004 i
    int*   v_start= e_start + 20004;            // 100004 i
    int*   bsum_e = v_start + 100004;           // 64 i
    int*   bsum_v = bsum_e + 64;                // 128 i
    int*   s_node = bsum_v + 128;               // 640000 i
    int*   s_edge = s_node + 640000;            // 640000 i
    float* Wcat   = (float*)(s_edge + 640000);  // 163840 f
    float* bcat   = Wcat + 163840;              // 640 f
    float* Binv   = bcat + 640;                 // 20000 f
    float* Dinv   = Binv + 20000;               // 100000 f
    ushort_t* xb     = (ushort_t*)(Dinv + 100000);  // 25,600,000 us (16B-aligned)
    ushort_t* agg_eb = xb + 25600000;               // 5,120,000 us
    ushort_t* geb    = agg_eb + 5120000;            // 12,800,000 us

    size_t zero_bytes = (size_t)(8 + 128 + 20000 + 100000 + 20000 + 100000) * 4;
    hipMemsetAsync(dsum, 0, zero_bytes, stream);

    k_degrees<<<(NNZ + 255) / 256, 256, 0, stream>>>(nidx, eidx, deg_e, deg_v);
    k_invert<<<(N_EDGES + 255) / 256, 256, 0, stream>>>(deg_e, Binv, N_EDGES);
    k_invert<<<(N_NODES + 255) / 256, 256, 0, stream>>>(deg_v, Dinv, N_NODES);

    int nbe = (N_EDGES + 1023) / 1024;   // 20
    int nbv = (N_NODES + 1023) / 1024;   // 98
    k_chunk_sums<<<nbe, 256, 0, stream>>>(deg_e, bsum_e, N_EDGES);
    k_scan_bsum<<<1, 128, 0, stream>>>(bsum_e, nbe, e_start, N_EDGES);
    k_scan_final<<<nbe, 1024, 0, stream>>>(deg_e, bsum_e, e_start, N_EDGES);
    k_chunk_sums<<<nbv, 256, 0, stream>>>(deg_v, bsum_v, N_NODES);
    k_scan_bsum<<<1, 128, 0, stream>>>(bsum_v, nbv, v_start, N_NODES);
    k_scan_final<<<nbv, 1024, 0, stream>>>(deg_v, bsum_v, v_start, N_NODES);

    k_fill<<<(NNZ + 255) / 256, 256, 0, stream>>>(nidx, eidx, e_start, v_start,
                                                  cur_e, cur_v, s_node, s_edge);

    k_wcat<<<(C * HCOLS + 255) / 256, 256, 0, stream>>>(convW, trW, attnW1, Wcat);
    k_bcat<<<1, 640, 0, stream>>>(convb, trb, trW, attnW1, attnb1, bcat);

    k_xcast<<<25000, 256, 0, stream>>>((const float4*)x, (ushort4*)xb);

    k_gather_e<<<N_EDGES / 8, 256, 0, stream>>>(s_node, e_start, xb, Binv, agg_eb);

    int row_blocks = (N_EDGES + BM - 1) / BM;   // 157
    k_gemm_e<<<row_blocks * 10, 256, 0, stream>>>(agg_eb, Wcat, geb);

    k_attn<<<N_NODES / 4, 256, 0, stream>>>(s_edge, v_start, geb, Dinv, bcat,
                                            attnW2, attnb2, dslots);
    k_dsum_final<<<1, 64, 0, stream>>>(dslots, sw, dsum);

    k_out<<<N_NODES / 4, 256, 0, stream>>>(s_edge, v_start, geb, Dinv, bcat,
                                           ln_g, ln_b, dsum, out);
}

// Round 9
// 681.204 us; speedup vs baseline: 7.9462x; 1.1454x over previous
//
#include <hip/hip_runtime.h>
#include <math.h>

#define N_NODES 100000
#define N_EDGES 20000
#define NNZ     640000
#define C       256
#define ATT_H   128
#define HCOLS   640   // ge cols: 256 (h0) + 256 (h1) + 128 (a1)
#define EPS     1e-5f
#define NPART   25000 // k_attn grid size (N_NODES/4), one partial pair per block

typedef unsigned short ushort_t;
typedef unsigned int uint_t;

__device__ __forceinline__ ushort_t f2bf(float f) {
    union { float f; unsigned u; } v; v.f = f;
    unsigned r = v.u + 0x7FFFu + ((v.u >> 16) & 1u);  // RNE
    return (ushort_t)(r >> 16);
}
__device__ __forceinline__ float bflo(uint_t u) {
    union { unsigned u; float f; } v; v.u = u << 16; return v.f;
}
__device__ __forceinline__ float bfhi(uint_t u) {
    union { unsigned u; float f; } v; v.u = u & 0xFFFF0000u; return v.f;
}
__device__ __forceinline__ uint_t pack2(float lo, float hi) {
    return (uint_t)f2bf(lo) | ((uint_t)f2bf(hi) << 16);
}

// ---------------- K1: integer degree histograms ----------------
__global__ __launch_bounds__(256)
void k_degrees(const int* __restrict__ nidx, const int* __restrict__ eidx,
               int* __restrict__ deg_e, int* __restrict__ deg_v) {
    int j = blockIdx.x * blockDim.x + threadIdx.x;
    if (j < NNZ) {
        atomicAdd(&deg_e[eidx[j]], 1);
        atomicAdd(&deg_v[nidx[j]], 1);
    }
}

__global__ __launch_bounds__(256)
void k_invert(const int* __restrict__ cnt, float* __restrict__ inv, int n) {
    int i = blockIdx.x * blockDim.x + threadIdx.x;
    if (i < n) { int d = cnt[i]; inv[i] = d > 0 ? 1.f / (float)d : 0.f; }
}

// ---------------- K2: 3-phase multi-block exclusive scan --------------------
__global__ __launch_bounds__(256)
void k_chunk_sums(const int* __restrict__ cnt, int* __restrict__ bsum, int n) {
    int base = blockIdx.x * 1024;
    int s = 0;
    for (int i = threadIdx.x; i < 1024; i += 256) {
        int g = base + i;
        s += (g < n) ? cnt[g] : 0;
    }
#pragma unroll
    for (int off = 32; off; off >>= 1) s += __shfl_down(s, off);
    __shared__ int red[4];
    int wave = threadIdx.x >> 6, lane = threadIdx.x & 63;
    if (lane == 0) red[wave] = s;
    __syncthreads();
    if (threadIdx.x == 0) bsum[blockIdx.x] = red[0] + red[1] + red[2] + red[3];
}

__global__ __launch_bounds__(128)
void k_scan_bsum(int* __restrict__ bsum, int nb, int* __restrict__ start, int n) {
    __shared__ int tmp[128];
    int v = (threadIdx.x < nb) ? bsum[threadIdx.x] : 0;
    tmp[threadIdx.x] = v;
    __syncthreads();
    for (int off = 1; off < 128; off <<= 1) {
        int a = (threadIdx.x >= off) ? tmp[threadIdx.x - off] : 0;
        __syncthreads();
        tmp[threadIdx.x] += a;
        __syncthreads();
    }
    if (threadIdx.x < nb) bsum[threadIdx.x] = tmp[threadIdx.x] - v;  // exclusive
    if (threadIdx.x == nb - 1) start[n] = tmp[threadIdx.x];          // total
}

__global__ __launch_bounds__(1024)
void k_scan_final(const int* __restrict__ cnt, const int* __restrict__ bsum,
                  int* __restrict__ start, int n) {
    __shared__ int tmp[1024];
    int i = blockIdx.x * 1024 + threadIdx.x;
    int v = (i < n) ? cnt[i] : 0;
    tmp[threadIdx.x] = v;
    __syncthreads();
    for (int off = 1; off < 1024; off <<= 1) {
        int a = (threadIdx.x >= off) ? tmp[threadIdx.x - off] : 0;
        __syncthreads();
        tmp[threadIdx.x] += a;
        __syncthreads();
    }
    if (i < n) start[i] = bsum[blockIdx.x] + tmp[threadIdx.x] - v;  // exclusive
}

// ---------------- K3: fill CSR adjacency ------------------------------------
__global__ __launch_bounds__(256)
void k_fill(const int* __restrict__ nidx, const int* __restrict__ eidx,
            const int* __restrict__ e_start, const int* __restrict__ v_start,
            int* __restrict__ cur_e, int* __restrict__ cur_v,
            int* __restrict__ sorted_node, int* __restrict__ sorted_edge) {
    int j = blockIdx.x * blockDim.x + threadIdx.x;
    if (j < NNZ) {
        int n = nidx[j], e = eidx[j];
        int pe = atomicAdd(&cur_e[e], 1);
        sorted_node[e_start[e] + pe] = n;
        int pv = atomicAdd(&cur_v[n], 1);
        sorted_edge[v_start[n] + pv] = e;
    }
}

// ---------------- K4: x -> bf16 copy ----------------------------------------
__global__ __launch_bounds__(256)
void k_xcast(const float4* __restrict__ x4, ushort4* __restrict__ xb4) {
    int i = blockIdx.x * blockDim.x + threadIdx.x;   // 6,400,000 float4s
    float4 v = x4[i];
    ushort4 o;
    o.x = f2bf(v.x); o.y = f2bf(v.y); o.z = f2bf(v.z); o.w = f2bf(v.w);
    xb4[i] = o;
}

// ---------------- K5: per-edge gather (bf16 x -> bf16 agg_e) ----------------
__global__ __launch_bounds__(256)
void k_gather_e(const int* __restrict__ sorted_node, const int* __restrict__ e_start,
                const ushort_t* __restrict__ xb, const float* __restrict__ Binv,
                ushort_t* __restrict__ agg_eb) {
    int wv = threadIdx.x >> 6;
    int lane = threadIdx.x & 63;
    int half = lane >> 5;
    int cl = lane & 31;
    int e = blockIdx.x * 8 + wv * 2 + half;
    int s = e_start[e], t = e_start[e + 1];
    float acc[8];
#pragma unroll
    for (int j = 0; j < 8; j++) acc[j] = 0.f;
    for (int p = s; p < t; ++p) {
        int n = sorted_node[p];
        uint4 raw = *reinterpret_cast<const uint4*>(xb + (size_t)n * C + cl * 8);
        acc[0] += bflo(raw.x); acc[1] += bfhi(raw.x);
        acc[2] += bflo(raw.y); acc[3] += bfhi(raw.y);
        acc[4] += bflo(raw.z); acc[5] += bfhi(raw.z);
        acc[6] += bflo(raw.w); acc[7] += bfhi(raw.w);
    }
    float bi = Binv[e];
    uint4 o;
    o.x = pack2(acc[0] * bi, acc[1] * bi);
    o.y = pack2(acc[2] * bi, acc[3] * bi);
    o.z = pack2(acc[4] * bi, acc[5] * bi);
    o.w = pack2(acc[6] * bi, acc[7] * bi);
    *reinterpret_cast<uint4*>(agg_eb + (size_t)e * C + cl * 8) = o;
}

// ---------------- K6: fused weight matrix Wcat [256][640] (f32) -------------
__global__ __launch_bounds__(256)
void k_wcat(const float* __restrict__ convW, const float* __restrict__ trW,
            const float* __restrict__ attnW1, float* __restrict__ Wcat) {
    int tid = blockIdx.x * blockDim.x + threadIdx.x;
    if (tid >= C * HCOLS) return;
    int k = tid / HCOLS, j = tid % HCOLS;
    float acc = 0.f;
    if (j < C) {
        for (int m = 0; m < C; m++) acc += convW[k * C + m] * trW[m * C + j];
    } else if (j < 2 * C) {
        int j2 = j - C;
        for (int m = 0; m < C; m++) acc += convW[C * C + k * C + m] * trW[C * C + m * C + j2];
    } else {
        int ja = j - 2 * C;
        for (int m = 0; m < C; m++)
            acc += 0.5f * (convW[k * C + m] + convW[C * C + k * C + m]) * attnW1[m * ATT_H + ja];
    }
    Wcat[(size_t)k * HCOLS + j] = acc;
}

__global__ __launch_bounds__(640)
void k_bcat(const float* __restrict__ convb, const float* __restrict__ trb,
            const float* __restrict__ trW, const float* __restrict__ attnW1,
            const float* __restrict__ attnb1, float* __restrict__ bcat) {
    int j = threadIdx.x;
    if (j >= HCOLS) return;
    float acc = 0.f;
    if (j < C) {
        for (int m = 0; m < C; m++) acc += convb[m] * trW[m * C + j];
        acc += trb[j];
    } else if (j < 2 * C) {
        int j2 = j - C;
        for (int m = 0; m < C; m++) acc += convb[C + m] * trW[C * C + m * C + j2];
        acc += trb[C + j2];
    } else {
        int ja = j - 2 * C;
        for (int m = 0; m < C; m++)
            acc += 0.5f * (convb[m] + convb[C + m]) * attnW1[m * ATT_H + ja];
        acc += attnb1[ja];
    }
    bcat[j] = acc;
}

// ---------------- K7: GEMM  ge[20000x640](bf16) = agg_e(bf16) @ Wcat(f32) ---
#define BM 128
#define BN 64
#define BK 32
__global__ __launch_bounds__(256)
void k_gemm_e(const ushort_t* __restrict__ Ab, const float* __restrict__ Wcat,
              ushort_t* __restrict__ geb) {
    __shared__ float As[BK][BM + 4];
    __shared__ float Bs[BK][BN + 4];
    const int t = threadIdx.x;
    const int tx = t & 15, ty = t >> 4;
    const int by = blockIdx.x / 10;
    const int bx = blockIdx.x % 10;
    const int row0 = by * BM;
    const int col0 = bx * BN;

    float acc[8][4];
#pragma unroll
    for (int i = 0; i < 8; i++)
#pragma unroll
        for (int j = 0; j < 4; j++) acc[i][j] = 0.f;

    for (int kb = 0; kb < C; kb += BK) {
#pragma unroll
        for (int i = 0; i < 2; i++) {
            int g = t + i * 256;
            int kg = g & 3;
            int r  = g >> 2;
            int row = row0 + r;
            uint4 raw = make_uint4(0u, 0u, 0u, 0u);
            if (row < N_EDGES)
                raw = *reinterpret_cast<const uint4*>(Ab + (size_t)row * C + kb + kg * 8);
            int k0 = kg * 8;
            As[k0 + 0][r] = bflo(raw.x); As[k0 + 1][r] = bfhi(raw.x);
            As[k0 + 2][r] = bflo(raw.y); As[k0 + 3][r] = bfhi(raw.y);
            As[k0 + 4][r] = bflo(raw.z); As[k0 + 5][r] = bfhi(raw.z);
            As[k0 + 6][r] = bflo(raw.w); As[k0 + 7][r] = bfhi(raw.w);
        }
#pragma unroll
        for (int i = 0; i < 2; i++) {
            int f4 = t + i * 256;
            int c4 = f4 & 15;
            int kk = f4 >> 4;
            float4 v = *reinterpret_cast<const float4*>(
                Wcat + (size_t)(kb + kk) * HCOLS + col0 + c4 * 4);
            *reinterpret_cast<float4*>(&Bs[kk][c4 * 4]) = v;
        }
        __syncthreads();
#pragma unroll
        for (int kk = 0; kk < BK; ++kk) {
            float4 b4 = *reinterpret_cast<const float4*>(&Bs[kk][tx * 4]);
            float4 a0 = *reinterpret_cast<const float4*>(&As[kk][ty * 8]);
            float4 a1 = *reinterpret_cast<const float4*>(&As[kk][ty * 8 + 4]);
            float a[8] = {a0.x, a0.y, a0.z, a0.w, a1.x, a1.y, a1.z, a1.w};
            float b[4] = {b4.x, b4.y, b4.z, b4.w};
#pragma unroll
            for (int i = 0; i < 8; i++)
#pragma unroll
                for (int j = 0; j < 4; j++) acc[i][j] += a[i] * b[j];
        }
        __syncthreads();
    }
#pragma unroll
    for (int i = 0; i < 8; i++) {
        int row = row0 + ty * 8 + i;
        if (row < N_EDGES) {
            ushort4 o;
            o.x = f2bf(acc[i][0]); o.y = f2bf(acc[i][1]);
            o.z = f2bf(acc[i][2]); o.w = f2bf(acc[i][3]);
            *reinterpret_cast<ushort4*>(geb + (size_t)row * HCOLS + col0 + tx * 4) = o;
        }
    }
}

// ---------------- K8 pass1: attn-slice gather -> per-block partial stores ---
__global__ __launch_bounds__(256)
void k_attn(const int* __restrict__ sorted_edge, const int* __restrict__ v_start,
            const ushort_t* __restrict__ geb, const float* __restrict__ Dinv,
            const float* __restrict__ bcat, const float* __restrict__ W2,
            const float* __restrict__ b2, float* __restrict__ part) {
    int n = blockIdx.x * 4 + (threadIdx.x >> 6);
    int lane = threadIdx.x & 63;
    int sub = lane >> 4;
    int cl  = lane & 15;
    float acc[8];
#pragma unroll
    for (int j = 0; j < 8; j++) acc[j] = 0.f;
    int s = v_start[n], t = v_start[n + 1];
    for (int p = s; p < t; p += 4) {
        int idx = p + sub;
        if (idx < t) {
            int e = sorted_edge[idx];
            uint4 raw = *reinterpret_cast<const uint4*>(geb + (size_t)e * HCOLS + 512 + cl * 8);
            acc[0] += bflo(raw.x); acc[1] += bfhi(raw.x);
            acc[2] += bflo(raw.y); acc[3] += bfhi(raw.y);
            acc[4] += bflo(raw.z); acc[5] += bfhi(raw.z);
            acc[6] += bflo(raw.w); acc[7] += bfhi(raw.w);
        }
    }
#pragma unroll
    for (int j = 0; j < 8; j++) {
        acc[j] += __shfl_xor(acc[j], 16);
        acc[j] += __shfl_xor(acc[j], 32);
    }
    float di = Dinv[n];
    float L0 = 0.f, L1 = 0.f;
#pragma unroll
    for (int j = 0; j < 8; j++) {
        int c = cl * 8 + j;
        float r = fmaxf(acc[j] * di + bcat[512 + c], 0.f);
        L0 += r * W2[c * 2 + 0];
        L1 += r * W2[c * 2 + 1];
    }
#pragma unroll
    for (int off = 8; off; off >>= 1) {
        L0 += __shfl_xor(L0, off);
        L1 += __shfl_xor(L1, off);
    }
    __shared__ float red[4][2];
    int wave = threadIdx.x >> 6;
    if (lane == 0) {
        L0 += b2[0]; L1 += b2[1];
        float mx = fmaxf(L0, L1);
        float e0 = expf(L0 - mx), e1 = expf(L1 - mx);
        float inv = 1.f / (e0 + e1);
        red[wave][0] = e0 * inv;
        red[wave][1] = e1 * inv;
    }
    __syncthreads();
    if (threadIdx.x == 0) {
        part[blockIdx.x * 2 + 0] = red[0][0] + red[1][0] + red[2][0] + red[3][0];
        part[blockIdx.x * 2 + 1] = red[0][1] + red[1][1] + red[2][1] + red[3][1];
    }
}

// reduce NPART partial pairs and finalize w = 0.5*(softmax(sw) + dyn_mean)
__global__ __launch_bounds__(256)
void k_dsum_final(const float* __restrict__ part, const float* __restrict__ sw,
                  float* __restrict__ dsum) {
    float p0 = 0.f, p1 = 0.f;
    for (int i = threadIdx.x; i < NPART; i += 256) {
        float2 v = *reinterpret_cast<const float2*>(part + i * 2);
        p0 += v.x; p1 += v.y;
    }
#pragma unroll
    for (int off = 32; off; off >>= 1) {
        p0 += __shfl_down(p0, off);
        p1 += __shfl_down(p1, off);
    }
    __shared__ float red[4][2];
    int wave = threadIdx.x >> 6, lane = threadIdx.x & 63;
    if (lane == 0) { red[wave][0] = p0; red[wave][1] = p1; }
    __syncthreads();
    if (threadIdx.x == 0) {
        p0 = red[0][0] + red[1][0] + red[2][0] + red[3][0];
        p1 = red[0][1] + red[1][1] + red[2][1] + red[3][1];
        float a0 = sw[0], a1 = sw[1];
        float mx = fmaxf(a0, a1);
        float e0 = expf(a0 - mx), e1 = expf(a1 - mx);
        float inv = 1.f / (e0 + e1);
        dsum[0] = 0.5f * (e0 * inv + p0 * (1.f / N_NODES));
        dsum[1] = 0.5f * (e1 * inv + p1 * (1.f / N_NODES));
    }
}

// ---------------- K9 pass2: main gather + LN + ReLU + combine -> out --------
// half-wave per scale: lane<32 -> h0 cols, lane>=32 -> h1 cols; 8 cols/lane
__global__ __launch_bounds__(256)
void k_out(const int* __restrict__ sorted_edge, const int* __restrict__ v_start,
           const ushort_t* __restrict__ geb, const float* __restrict__ Dinv,
           const float* __restrict__ bcat, const float* __restrict__ ln_g,
           const float* __restrict__ ln_b, const float* __restrict__ dsum,
           float* __restrict__ out) {
    int n = blockIdx.x * 4 + (threadIdx.x >> 6);
    int lane = threadIdx.x & 63;
    int half = lane >> 5;           // which scale's column segment
    int cl = lane & 31;             // col group: cols cl*8 .. +7
    int cbase = half * 256 + cl * 8;
    float acc[8];
#pragma unroll
    for (int j = 0; j < 8; j++) acc[j] = 0.f;
    int s = v_start[n], t = v_start[n + 1];
    int p = s;
    for (; p + 1 < t; p += 2) {
        int e0 = sorted_edge[p], e1 = sorted_edge[p + 1];
        uint4 r0 = *reinterpret_cast<const uint4*>(geb + (size_t)e0 * HCOLS + cbase);
        uint4 r1 = *reinterpret_cast<const uint4*>(geb + (size_t)e1 * HCOLS + cbase);
        acc[0] += bflo(r0.x) + bflo(r1.x); acc[1] += bfhi(r0.x) + bfhi(r1.x);
        acc[2] += bflo(r0.y) + bflo(r1.y); acc[3] += bfhi(r0.y) + bfhi(r1.y);
        acc[4] += bflo(r0.z) + bflo(r1.z); acc[5] += bfhi(r0.z) + bfhi(r1.z);
        acc[6] += bflo(r0.w) + bflo(r1.w); acc[7] += bfhi(r0.w) + bfhi(r1.w);
    }
    if (p < t) {
        int e0 = sorted_edge[p];
        uint4 r0 = *reinterpret_cast<const uint4*>(geb + (size_t)e0 * HCOLS + cbase);
        acc[0] += bflo(r0.x); acc[1] += bfhi(r0.x);
        acc[2] += bflo(r0.y); acc[3] += bfhi(r0.y);
        acc[4] += bflo(r0.z); acc[5] += bfhi(r0.z);
        acc[6] += bflo(r0.w); acc[7] += bfhi(r0.w);
    }
    float di = Dinv[n];
    float h[8];
    float4 bA = *reinterpret_cast<const float4*>(bcat + cbase);
    float4 bB = *reinterpret_cast<const float4*>(bcat + cbase + 4);
    h[0] = acc[0] * di + bA.x; h[1] = acc[1] * di + bA.y;
    h[2] = acc[2] * di + bA.z; h[3] = acc[3] * di + bA.w;
    h[4] = acc[4] * di + bB.x; h[5] = acc[5] * di + bB.y;
    h[6] = acc[6] * di + bB.z; h[7] = acc[7] * di + bB.w;

    float s_ = 0.f, q_ = 0.f;
#pragma unroll
    for (int j = 0; j < 8; j++) { s_ += h[j]; q_ += h[j] * h[j]; }
#pragma unroll
    for (int off = 16; off; off >>= 1) {   // reduce within the 32-lane half
        s_ += __shfl_xor(s_, off);
        q_ += __shfl_xor(q_, off);
    }
    const float invC = 1.f / 256.f;
    float mu = s_ * invC;
    float var = q_ * invC - mu * mu;
    float rs = rsqrtf(var + EPS);

    float4 gA = *reinterpret_cast<const float4*>(ln_g + cbase);
    float4 gB = *reinterpret_cast<const float4*>(ln_g + cbase + 4);
    float4 lA = *reinterpret_cast<const float4*>(ln_b + cbase);
    float4 lB = *reinterpret_cast<const float4*>(ln_b + cbase + 4);
    float g[8] = {gA.x, gA.y, gA.z, gA.w, gB.x, gB.y, gB.z, gB.w};
    float l[8] = {lA.x, lA.y, lA.z, lA.w, lB.x, lB.y, lB.z, lB.w};

    float w0 = dsum[0], w1 = dsum[1];
    float wa = half ? w1 : w0;   // weight for own scale
    float wb = half ? w0 : w1;   // weight for partner scale
    float o[8];
#pragma unroll
    for (int j = 0; j < 8; j++) {
        float tv = fmaxf((h[j] - mu) * rs * g[j] + l[j], 0.f);
        float other = __shfl_xor(tv, 32);
        o[j] = wa * tv + wb * other;
    }
    // lane<32 writes cols cl*8..+3 (o[0..3]); lane>=32 writes cl*8+4..+7 (o[4..7])
    float4 ov;
    if (half == 0) ov = make_float4(o[0], o[1], o[2], o[3]);
    else           ov = make_float4(o[4], o[5], o[6], o[7]);
    *reinterpret_cast<float4*>(out + (size_t)n * C + cl * 8 + half * 4) = ov;
}

// ---------------- launch ----------------
extern "C" void kernel_launch(void* const* d_in, const int* in_sizes, int n_in,
                              void* d_out, int out_size, void* d_ws, size_t ws_size,
                              hipStream_t stream) {
    const float* x       = (const float*)d_in[0];
    const int*   he      = (const int*)d_in[1];
    const int*   nidx    = he;
    const int*   eidx    = he + NNZ;
    const float* convW   = (const float*)d_in[2];
    const float* convb   = (const float*)d_in[3];
    const float* trW     = (const float*)d_in[4];
    const float* trb     = (const float*)d_in[5];
    const float* ln_g    = (const float*)d_in[6];
    const float* ln_b    = (const float*)d_in[7];
    const float* sw      = (const float*)d_in[8];
    const float* attnW1  = (const float*)d_in[9];
    const float* attnb1  = (const float*)d_in[10];
    const float* attnW2  = (const float*)d_in[11];
    const float* attnb2  = (const float*)d_in[12];
    float* out = (float*)d_out;

    // workspace layout
    float* ws     = (float*)d_ws;
    float* dsum   = ws;                         // 8 f   (written by k_dsum_final)
    float* part   = dsum + 8;                   // 50000 f (fully written by k_attn)
    // --- zeroed region start ---
    int*   deg_e  = (int*)(part + 50000);       // 20000 i
    int*   deg_v  = deg_e + 20000;              // 100000 i
    int*   cur_e  = deg_v + 100000;             // 20000 i
    int*   cur_v  = cur_e + 20000;              // 100000 i
    // --- zeroed region end (240000 words) ---
    int*   e_start= cur_v + 100000;             // 20004 i
    int*   v_start= e_start + 20004;            // 100004 i
    int*   bsum_e = v_start + 100004;           // 64 i
    int*   bsum_v = bsum_e + 64;                // 128 i
    int*   s_node = bsum_v + 128;               // 640000 i
    int*   s_edge = s_node + 640000;            // 640000 i
    float* Wcat   = (float*)(s_edge + 640000);  // 163840 f
    float* bcat   = Wcat + 163840;              // 640 f
    float* Binv   = bcat + 640;                 // 20000 f
    float* Dinv   = Binv + 20000;               // 100000 f
    ushort_t* xb     = (ushort_t*)(Dinv + 100000);  // 25,600,000 us
    ushort_t* agg_eb = xb + 25600000;               // 5,120,000 us
    ushort_t* geb    = agg_eb + 5120000;            // 12,800,000 us

    size_t zero_bytes = (size_t)(20000 + 100000 + 20000 + 100000) * 4;
    hipMemsetAsync(deg_e, 0, zero_bytes, stream);

    k_degrees<<<(NNZ + 255) / 256, 256, 0, stream>>>(nidx, eidx, deg_e, deg_v);
    k_invert<<<(N_EDGES + 255) / 256, 256, 0, stream>>>(deg_e, Binv, N_EDGES);
    k_invert<<<(N_NODES + 255) / 256, 256, 0, stream>>>(deg_v, Dinv, N_NODES);

    int nbe = (N_EDGES + 1023) / 1024;   // 20
    int nbv = (N_NODES + 1023) / 1024;   // 98
    k_chunk_sums<<<nbe, 256, 0, stream>>>(deg_e, bsum_e, N_EDGES);
    k_scan_bsum<<<1, 128, 0, stream>>>(bsum_e, nbe, e_start, N_EDGES);
    k_scan_final<<<nbe, 1024, 0, stream>>>(deg_e, bsum_e, e_start, N_EDGES);
    k_chunk_sums<<<nbv, 256, 0, stream>>>(deg_v, bsum_v, N_NODES);
    k_scan_bsum<<<1, 128, 0, stream>>>(bsum_v, nbv, v_start, N_NODES);
    k_scan_final<<<nbv, 1024, 0, stream>>>(deg_v, bsum_v, v_start, N_NODES);

    k_fill<<<(NNZ + 255) / 256, 256, 0, stream>>>(nidx, eidx, e_start, v_start,
                                                  cur_e, cur_v, s_node, s_edge);

    k_wcat<<<(C * HCOLS + 255) / 256, 256, 0, stream>>>(convW, trW, attnW1, Wcat);
    k_bcat<<<1, 640, 0, stream>>>(convb, trb, trW, attnW1, attnb1, bcat);

    k_xcast<<<25000, 256, 0, stream>>>((const float4*)x, (ushort4*)xb);

    k_gather_e<<<N_EDGES / 8, 256, 0, stream>>>(s_node, e_start, xb, Binv, agg_eb);

    int row_blocks = (N_EDGES + BM - 1) / BM;   // 157
    k_gemm_e<<<row_blocks * 10, 256, 0, stream>>>(agg_eb, Wcat, geb);

    k_attn<<<NPART, 256, 0, stream>>>(s_edge, v_start, geb, Dinv, bcat,
                                      attnW2, attnb2, part);
    k_dsum_final<<<1, 256, 0, stream>>>(part, sw, dsum);

    k_out<<<N_NODES / 4, 256, 0, stream>>>(s_edge, v_start, geb, Dinv, bcat,
                                           ln_g, ln_b, dsum, out);
}

// Round 10
// 655.591 us; speedup vs baseline: 8.2567x; 1.0391x over previous
//
#include <hip/hip_runtime.h>
#include <math.h>

#define N_NODES 100000
#define N_EDGES 20000
#define NEPAD   20096 // padded edge rows for guard-free MFMA GEMM (157*128)
#define NNZ     640000
#define C       256
#define ATT_H   128
#define HCOLS   640   // ge cols: 256 (h0) + 256 (h1) + 128 (a1)
#define EPS     1e-5f
#define NPART   25000 // k_attn grid size (N_NODES/4), one partial pair per block

typedef unsigned short ushort_t;
typedef unsigned int uint_t;
typedef __attribute__((ext_vector_type(8))) short bf16x8;
typedef __attribute__((ext_vector_type(4))) float f32x4;

__device__ __forceinline__ ushort_t f2bf(float f) {
    union { float f; unsigned u; } v; v.f = f;
    unsigned r = v.u + 0x7FFFu + ((v.u >> 16) & 1u);  // RNE
    return (ushort_t)(r >> 16);
}
__device__ __forceinline__ float bflo(uint_t u) {
    union { unsigned u; float f; } v; v.u = u << 16; return v.f;
}
__device__ __forceinline__ float bfhi(uint_t u) {
    union { unsigned u; float f; } v; v.u = u & 0xFFFF0000u; return v.f;
}
__device__ __forceinline__ uint_t pack2(float lo, float hi) {
    return (uint_t)f2bf(lo) | ((uint_t)f2bf(hi) << 16);
}

// ---------------- K1: integer degree histograms ----------------
__global__ __launch_bounds__(256)
void k_degrees(const int* __restrict__ nidx, const int* __restrict__ eidx,
               int* __restrict__ deg_e, int* __restrict__ deg_v) {
    int j = blockIdx.x * blockDim.x + threadIdx.x;
    if (j < NNZ) {
        atomicAdd(&deg_e[eidx[j]], 1);
        atomicAdd(&deg_v[nidx[j]], 1);
    }
}

__global__ __launch_bounds__(256)
void k_invert(const int* __restrict__ cnt, float* __restrict__ inv, int n) {
    int i = blockIdx.x * blockDim.x + threadIdx.x;
    if (i < n) { int d = cnt[i]; inv[i] = d > 0 ? 1.f / (float)d : 0.f; }
}

// ---------------- K2: 3-phase multi-block exclusive scan --------------------
__global__ __launch_bounds__(256)
void k_chunk_sums(const int* __restrict__ cnt, int* __restrict__ bsum, int n) {
    int base = blockIdx.x * 1024;
    int s = 0;
    for (int i = threadIdx.x; i < 1024; i += 256) {
        int g = base + i;
        s += (g < n) ? cnt[g] : 0;
    }
#pragma unroll
    for (int off = 32; off; off >>= 1) s += __shfl_down(s, off);
    __shared__ int red[4];
    int wave = threadIdx.x >> 6, lane = threadIdx.x & 63;
    if (lane == 0) red[wave] = s;
    __syncthreads();
    if (threadIdx.x == 0) bsum[blockIdx.x] = red[0] + red[1] + red[2] + red[3];
}

__global__ __launch_bounds__(128)
void k_scan_bsum(int* __restrict__ bsum, int nb, int* __restrict__ start, int n) {
    __shared__ int tmp[128];
    int v = (threadIdx.x < nb) ? bsum[threadIdx.x] : 0;
    tmp[threadIdx.x] = v;
    __syncthreads();
    for (int off = 1; off < 128; off <<= 1) {
        int a = (threadIdx.x >= off) ? tmp[threadIdx.x - off] : 0;
        __syncthreads();
        tmp[threadIdx.x] += a;
        __syncthreads();
    }
    if (threadIdx.x < nb) bsum[threadIdx.x] = tmp[threadIdx.x] - v;  // exclusive
    if (threadIdx.x == nb - 1) start[n] = tmp[threadIdx.x];          // total
}

__global__ __launch_bounds__(1024)
void k_scan_final(const int* __restrict__ cnt, const int* __restrict__ bsum,
                  int* __restrict__ start, int n) {
    __shared__ int tmp[1024];
    int i = blockIdx.x * 1024 + threadIdx.x;
    int v = (i < n) ? cnt[i] : 0;
    tmp[threadIdx.x] = v;
    __syncthreads();
    for (int off = 1; off < 1024; off <<= 1) {
        int a = (threadIdx.x >= off) ? tmp[threadIdx.x - off] : 0;
        __syncthreads();
        tmp[threadIdx.x] += a;
        __syncthreads();
    }
    if (i < n) start[i] = bsum[blockIdx.x] + tmp[threadIdx.x] - v;  // exclusive
}

// ---------------- K3: fill CSR adjacency ------------------------------------
__global__ __launch_bounds__(256)
void k_fill(const int* __restrict__ nidx, const int* __restrict__ eidx,
            const int* __restrict__ e_start, const int* __restrict__ v_start,
            int* __restrict__ cur_e, int* __restrict__ cur_v,
            int* __restrict__ sorted_node, int* __restrict__ sorted_edge) {
    int j = blockIdx.x * blockDim.x + threadIdx.x;
    if (j < NNZ) {
        int n = nidx[j], e = eidx[j];
        int pe = atomicAdd(&cur_e[e], 1);
        sorted_node[e_start[e] + pe] = n;
        int pv = atomicAdd(&cur_v[n], 1);
        sorted_edge[v_start[n] + pv] = e;
    }
}

// ---------------- K4: x -> bf16 copy ----------------------------------------
__global__ __launch_bounds__(256)
void k_xcast(const float4* __restrict__ x4, ushort4* __restrict__ xb4) {
    int i = blockIdx.x * blockDim.x + threadIdx.x;   // 6,400,000 float4s
    float4 v = x4[i];
    ushort4 o;
    o.x = f2bf(v.x); o.y = f2bf(v.y); o.z = f2bf(v.z); o.w = f2bf(v.w);
    xb4[i] = o;
}

// ---------------- K5: per-edge gather (bf16 x -> bf16 agg_e) ----------------
__global__ __launch_bounds__(256)
void k_gather_e(const int* __restrict__ sorted_node, const int* __restrict__ e_start,
                const ushort_t* __restrict__ xb, const float* __restrict__ Binv,
                ushort_t* __restrict__ agg_eb) {
    int wv = threadIdx.x >> 6;
    int lane = threadIdx.x & 63;
    int half = lane >> 5;
    int cl = lane & 31;
    int e = blockIdx.x * 8 + wv * 2 + half;
    int s = e_start[e], t = e_start[e + 1];
    float acc[8];
#pragma unroll
    for (int j = 0; j < 8; j++) acc[j] = 0.f;
    for (int p = s; p < t; ++p) {
        int n = sorted_node[p];
        uint4 raw = *reinterpret_cast<const uint4*>(xb + (size_t)n * C + cl * 8);
        acc[0] += bflo(raw.x); acc[1] += bfhi(raw.x);
        acc[2] += bflo(raw.y); acc[3] += bfhi(raw.y);
        acc[4] += bflo(raw.z); acc[5] += bfhi(raw.z);
        acc[6] += bflo(raw.w); acc[7] += bfhi(raw.w);
    }
    float bi = Binv[e];
    uint4 o;
    o.x = pack2(acc[0] * bi, acc[1] * bi);
    o.y = pack2(acc[2] * bi, acc[3] * bi);
    o.z = pack2(acc[4] * bi, acc[5] * bi);
    o.w = pack2(acc[6] * bi, acc[7] * bi);
    *reinterpret_cast<uint4*>(agg_eb + (size_t)e * C + cl * 8) = o;
}

// ---------------- K6: fused weights, transposed bf16: WcatbT[640][256] ------
// j = col (block-uniform), k = row; WcatbT[j][k] = Wcat[k][j]
__global__ __launch_bounds__(256)
void k_wcatT(const float* __restrict__ convW, const float* __restrict__ trW,
             const float* __restrict__ attnW1, ushort_t* __restrict__ BT) {
    int tid = blockIdx.x * 256 + threadIdx.x;   // 640*256
    int k = tid & 255;
    int j = tid >> 8;
    float acc = 0.f;
    if (j < C) {
        for (int m = 0; m < C; m++) acc += convW[k * C + m] * trW[m * C + j];
    } else if (j < 2 * C) {
        int j2 = j - C;
        for (int m = 0; m < C; m++) acc += convW[C * C + k * C + m] * trW[C * C + m * C + j2];
    } else {
        int ja = j - 2 * C;
        for (int m = 0; m < C; m++)
            acc += 0.5f * (convW[k * C + m] + convW[C * C + k * C + m]) * attnW1[m * ATT_H + ja];
    }
    BT[(size_t)j * C + k] = f2bf(acc);
}

__global__ __launch_bounds__(640)
void k_bcat(const float* __restrict__ convb, const float* __restrict__ trb,
            const float* __restrict__ trW, const float* __restrict__ attnW1,
            const float* __restrict__ attnb1, float* __restrict__ bcat) {
    int j = threadIdx.x;
    if (j >= HCOLS) return;
    float acc = 0.f;
    if (j < C) {
        for (int m = 0; m < C; m++) acc += convb[m] * trW[m * C + j];
        acc += trb[j];
    } else if (j < 2 * C) {
        int j2 = j - C;
        for (int m = 0; m < C; m++) acc += convb[C + m] * trW[C * C + m * C + j2];
        acc += trb[C + j2];
    } else {
        int ja = j - 2 * C;
        for (int m = 0; m < C; m++)
            acc += 0.5f * (convb[m] + convb[C + m]) * attnW1[m * ATT_H + ja];
        acc += attnb1[ja];
    }
    bcat[j] = acc;
}

// ---------------- K7: MFMA GEMM  ge[NEPAD x 640](bf16) = agg_e @ WcatbT^T ---
// 256 thr = 4 waves (2x2); wave tile 64x32 = 4x2 frags of 16x16, K-step 32.
// No LDS: per-lane fragments loaded directly from global (16B each).
// A frag: row=lane&15, k=(lane>>4)*8+j ; B frag: col=lane&15, k=(lane>>4)*8+j
// D frag: col=lane&15, row=(lane>>4)*4+reg  [m89-verified]
#define BM 128
#define BN 64
__global__ __launch_bounds__(256)
void k_gemm_e(const ushort_t* __restrict__ Ab, const ushort_t* __restrict__ BT,
              ushort_t* __restrict__ geb) {
    const int w = threadIdx.x >> 6;
    const int lane = threadIdx.x & 63;
    const int lr = lane & 15;
    const int lg = lane >> 4;
    const int by = blockIdx.x / 10;
    const int bx = blockIdx.x % 10;
    const int row0 = by * BM + (w >> 1) * 64;
    const int col0 = bx * BN + (w & 1) * 32;

    f32x4 acc[4][2];
#pragma unroll
    for (int mf = 0; mf < 4; mf++)
#pragma unroll
        for (int nf = 0; nf < 2; nf++) acc[mf][nf] = (f32x4){0.f, 0.f, 0.f, 0.f};

    const ushort_t* aptr[4];
#pragma unroll
    for (int mf = 0; mf < 4; mf++)
        aptr[mf] = Ab + (size_t)(row0 + mf * 16 + lr) * C + lg * 8;
    const ushort_t* bptr[2];
#pragma unroll
    for (int nf = 0; nf < 2; nf++)
        bptr[nf] = BT + (size_t)(col0 + nf * 16 + lr) * C + lg * 8;

#pragma unroll
    for (int kb = 0; kb < C; kb += 32) {
        bf16x8 a[4], b[2];
#pragma unroll
        for (int mf = 0; mf < 4; mf++)
            a[mf] = *reinterpret_cast<const bf16x8*>(aptr[mf] + kb);
#pragma unroll
        for (int nf = 0; nf < 2; nf++)
            b[nf] = *reinterpret_cast<const bf16x8*>(bptr[nf] + kb);
#pragma unroll
        for (int mf = 0; mf < 4; mf++)
#pragma unroll
            for (int nf = 0; nf < 2; nf++)
                acc[mf][nf] = __builtin_amdgcn_mfma_f32_16x16x32_bf16(
                    a[mf], b[nf], acc[mf][nf], 0, 0, 0);
    }

#pragma unroll
    for (int mf = 0; mf < 4; mf++) {
        int rbase = row0 + mf * 16 + lg * 4;
#pragma unroll
        for (int r = 0; r < 4; r++) {
            size_t rowoff = (size_t)(rbase + r) * HCOLS;
#pragma unroll
            for (int nf = 0; nf < 2; nf++)
                geb[rowoff + col0 + nf * 16 + lr] = f2bf(acc[mf][nf][r]);
        }
    }
}

// ---------------- K8 pass1: attn-slice gather -> per-block partial stores ---
__global__ __launch_bounds__(256)
void k_attn(const int* __restrict__ sorted_edge, const int* __restrict__ v_start,
            const ushort_t* __restrict__ geb, const float* __restrict__ Dinv,
            const float* __restrict__ bcat, const float* __restrict__ W2,
            const float* __restrict__ b2, float* __restrict__ part) {
    int n = blockIdx.x * 4 + (threadIdx.x >> 6);
    int lane = threadIdx.x & 63;
    int sub = lane >> 4;
    int cl  = lane & 15;
    float acc[8];
#pragma unroll
    for (int j = 0; j < 8; j++) acc[j] = 0.f;
    int s = v_start[n], t = v_start[n + 1];
    for (int p = s; p < t; p += 4) {
        int idx = p + sub;
        if (idx < t) {
            int e = sorted_edge[idx];
            uint4 raw = *reinterpret_cast<const uint4*>(geb + (size_t)e * HCOLS + 512 + cl * 8);
            acc[0] += bflo(raw.x); acc[1] += bfhi(raw.x);
            acc[2] += bflo(raw.y); acc[3] += bfhi(raw.y);
            acc[4] += bflo(raw.z); acc[5] += bfhi(raw.z);
            acc[6] += bflo(raw.w); acc[7] += bfhi(raw.w);
        }
    }
#pragma unroll
    for (int j = 0; j < 8; j++) {
        acc[j] += __shfl_xor(acc[j], 16);
        acc[j] += __shfl_xor(acc[j], 32);
    }
    float di = Dinv[n];
    float L0 = 0.f, L1 = 0.f;
#pragma unroll
    for (int j = 0; j < 8; j++) {
        int c = cl * 8 + j;
        float r = fmaxf(acc[j] * di + bcat[512 + c], 0.f);
        L0 += r * W2[c * 2 + 0];
        L1 += r * W2[c * 2 + 1];
    }
#pragma unroll
    for (int off = 8; off; off >>= 1) {
        L0 += __shfl_xor(L0, off);
        L1 += __shfl_xor(L1, off);
    }
    __shared__ float red[4][2];
    int wave = threadIdx.x >> 6;
    if (lane == 0) {
        L0 += b2[0]; L1 += b2[1];
        float mx = fmaxf(L0, L1);
        float e0 = expf(L0 - mx), e1 = expf(L1 - mx);
        float inv = 1.f / (e0 + e1);
        red[wave][0] = e0 * inv;
        red[wave][1] = e1 * inv;
    }
    __syncthreads();
    if (threadIdx.x == 0) {
        part[blockIdx.x * 2 + 0] = red[0][0] + red[1][0] + red[2][0] + red[3][0];
        part[blockIdx.x * 2 + 1] = red[0][1] + red[1][1] + red[2][1] + red[3][1];
    }
}

// reduce NPART partial pairs and finalize w = 0.5*(softmax(sw) + dyn_mean)
__global__ __launch_bounds__(256)
void k_dsum_final(const float* __restrict__ part, const float* __restrict__ sw,
                  float* __restrict__ dsum) {
    float p0 = 0.f, p1 = 0.f;
    for (int i = threadIdx.x; i < NPART; i += 256) {
        float2 v = *reinterpret_cast<const float2*>(part + i * 2);
        p0 += v.x; p1 += v.y;
    }
#pragma unroll
    for (int off = 32; off; off >>= 1) {
        p0 += __shfl_down(p0, off);
        p1 += __shfl_down(p1, off);
    }
    __shared__ float red[4][2];
    int wave = threadIdx.x >> 6, lane = threadIdx.x & 63;
    if (lane == 0) { red[wave][0] = p0; red[wave][1] = p1; }
    __syncthreads();
    if (threadIdx.x == 0) {
        p0 = red[0][0] + red[1][0] + red[2][0] + red[3][0];
        p1 = red[0][1] + red[1][1] + red[2][1] + red[3][1];
        float a0 = sw[0], a1 = sw[1];
        float mx = fmaxf(a0, a1);
        float e0 = expf(a0 - mx), e1 = expf(a1 - mx);
        float inv = 1.f / (e0 + e1);
        dsum[0] = 0.5f * (e0 * inv + p0 * (1.f / N_NODES));
        dsum[1] = 0.5f * (e1 * inv + p1 * (1.f / N_NODES));
    }
}

// ---------------- K9 pass2: main gather + LN + ReLU + combine -> out --------
__global__ __launch_bounds__(256)
void k_out(const int* __restrict__ sorted_edge, const int* __restrict__ v_start,
           const ushort_t* __restrict__ geb, const float* __restrict__ Dinv,
           const float* __restrict__ bcat, const float* __restrict__ ln_g,
           const float* __restrict__ ln_b, const float* __restrict__ dsum,
           float* __restrict__ out) {
    int n = blockIdx.x * 4 + (threadIdx.x >> 6);
    int lane = threadIdx.x & 63;
    int half = lane >> 5;
    int cl = lane & 31;
    int cbase = half * 256 + cl * 8;
    float acc[8];
#pragma unroll
    for (int j = 0; j < 8; j++) acc[j] = 0.f;
    int s = v_start[n], t = v_start[n + 1];
    int p = s;
    for (; p + 1 < t; p += 2) {
        int e0 = sorted_edge[p], e1 = sorted_edge[p + 1];
        uint4 r0 = *reinterpret_cast<const uint4*>(geb + (size_t)e0 * HCOLS + cbase);
        uint4 r1 = *reinterpret_cast<const uint4*>(geb + (size_t)e1 * HCOLS + cbase);
        acc[0] += bflo(r0.x) + bflo(r1.x); acc[1] += bfhi(r0.x) + bfhi(r1.x);
        acc[2] += bflo(r0.y) + bflo(r1.y); acc[3] += bfhi(r0.y) + bfhi(r1.y);
        acc[4] += bflo(r0.z) + bflo(r1.z); acc[5] += bfhi(r0.z) + bfhi(r1.z);
        acc[6] += bflo(r0.w) + bflo(r1.w); acc[7] += bfhi(r0.w) + bfhi(r1.w);
    }
    if (p < t) {
        int e0 = sorted_edge[p];
        uint4 r0 = *reinterpret_cast<const uint4*>(geb + (size_t)e0 * HCOLS + cbase);
        acc[0] += bflo(r0.x); acc[1] += bfhi(r0.x);
        acc[2] += bflo(r0.y); acc[3] += bfhi(r0.y);
        acc[4] += bflo(r0.z); acc[5] += bfhi(r0.z);
        acc[6] += bflo(r0.w); acc[7] += bfhi(r0.w);
    }
    float di = Dinv[n];
    float h[8];
    float4 bA = *reinterpret_cast<const float4*>(bcat + cbase);
    float4 bB = *reinterpret_cast<const float4*>(bcat + cbase + 4);
    h[0] = acc[0] * di + bA.x; h[1] = acc[1] * di + bA.y;
    h[2] = acc[2] * di + bA.z; h[3] = acc[3] * di + bA.w;
    h[4] = acc[4] * di + bB.x; h[5] = acc[5] * di + bB.y;
    h[6] = acc[6] * di + bB.z; h[7] = acc[7] * di + bB.w;

    float s_ = 0.f, q_ = 0.f;
#pragma unroll
    for (int j = 0; j < 8; j++) { s_ += h[j]; q_ += h[j] * h[j]; }
#pragma unroll
    for (int off = 16; off; off >>= 1) {
        s_ += __shfl_xor(s_, off);
        q_ += __shfl_xor(q_, off);
    }
    const float invC = 1.f / 256.f;
    float mu = s_ * invC;
    float var = q_ * invC - mu * mu;
    float rs = rsqrtf(var + EPS);

    float4 gA = *reinterpret_cast<const float4*>(ln_g + cbase);
    float4 gB = *reinterpret_cast<const float4*>(ln_g + cbase + 4);
    float4 lA = *reinterpret_cast<const float4*>(ln_b + cbase);
    float4 lB = *reinterpret_cast<const float4*>(ln_b + cbase + 4);
    float g[8] = {gA.x, gA.y, gA.z, gA.w, gB.x, gB.y, gB.z, gB.w};
    float l[8] = {lA.x, lA.y, lA.z, lA.w, lB.x, lB.y, lB.z, lB.w};

    float w0 = dsum[0], w1 = dsum[1];
    float wa = half ? w1 : w0;
    float wb = half ? w0 : w1;
    float o[8];
#pragma unroll
    for (int j = 0; j < 8; j++) {
        float tv = fmaxf((h[j] - mu) * rs * g[j] + l[j], 0.f);
        float other = __shfl_xor(tv, 32);
        o[j] = wa * tv + wb * other;
    }
    float4 ov;
    if (half == 0) ov = make_float4(o[0], o[1], o[2], o[3]);
    else           ov = make_float4(o[4], o[5], o[6], o[7]);
    *reinterpret_cast<float4*>(out + (size_t)n * C + cl * 8 + half * 4) = ov;
}

// ---------------- launch ----------------
extern "C" void kernel_launch(void* const* d_in, const int* in_sizes, int n_in,
                              void* d_out, int out_size, void* d_ws, size_t ws_size,
                              hipStream_t stream) {
    const float* x       = (const float*)d_in[0];
    const int*   he      = (const int*)d_in[1];
    const int*   nidx    = he;
    const int*   eidx    = he + NNZ;
    const float* convW   = (const float*)d_in[2];
    const float* convb   = (const float*)d_in[3];
    const float* trW     = (const float*)d_in[4];
    const float* trb     = (const float*)d_in[5];
    const float* ln_g    = (const float*)d_in[6];
    const float* ln_b    = (const float*)d_in[7];
    const float* sw      = (const float*)d_in[8];
    const float* attnW1  = (const float*)d_in[9];
    const float* attnb1  = (const float*)d_in[10];
    const float* attnW2  = (const float*)d_in[11];
    const float* attnb2  = (const float*)d_in[12];
    float* out = (float*)d_out;

    // workspace layout
    float* ws     = (float*)d_ws;
    float* dsum   = ws;                         // 8 f
    float* part   = dsum + 8;                   // 50000 f (fully written by k_attn)
    // --- zeroed region start ---
    int*   deg_e  = (int*)(part + 50000);       // 20000 i
    int*   deg_v  = deg_e + 20000;              // 100000 i
    int*   cur_e  = deg_v + 100000;             // 20000 i
    int*   cur_v  = cur_e + 20000;              // 100000 i
    // --- zeroed region end (240000 words) ---
    int*   e_start= cur_v + 100000;             // 20004 i
    int*   v_start= e_start + 20004;            // 100004 i
    int*   bsum_e = v_start + 100004;           // 64 i
    int*   bsum_v = bsum_e + 64;                // 128 i
    int*   s_node = bsum_v + 128;               // 640000 i
    int*   s_edge = s_node + 640000;            // 640000 i
    float* bcat   = (float*)(s_edge + 640000);  // 640 f
    float* Binv   = bcat + 640;                 // 20000 f
    float* Dinv   = Binv + 20000;               // 100000 f
    ushort_t* WcatbT = (ushort_t*)(Dinv + 100000);  // 163840 us [640][256]
    ushort_t* xb     = WcatbT + 163840;             // 25,600,000 us
    ushort_t* agg_eb = xb + 25600000;               // NEPAD*256 = 5,144,576 us
    ushort_t* geb    = agg_eb + (size_t)NEPAD * C;  // NEPAD*640 = 12,861,440 us

    size_t zero_bytes = (size_t)(20000 + 100000 + 20000 + 100000) * 4;
    hipMemsetAsync(deg_e, 0, zero_bytes, stream);
    // zero padded tail rows of agg_eb (rows 20000..20095) for guard-free GEMM
    hipMemsetAsync(agg_eb + (size_t)N_EDGES * C, 0,
                   (size_t)(NEPAD - N_EDGES) * C * sizeof(ushort_t), stream);

    k_degrees<<<(NNZ + 255) / 256, 256, 0, stream>>>(nidx, eidx, deg_e, deg_v);
    k_invert<<<(N_EDGES + 255) / 256, 256, 0, stream>>>(deg_e, Binv, N_EDGES);
    k_invert<<<(N_NODES + 255) / 256, 256, 0, stream>>>(deg_v, Dinv, N_NODES);

    int nbe = (N_EDGES + 1023) / 1024;   // 20
    int nbv = (N_NODES + 1023) / 1024;   // 98
    k_chunk_sums<<<nbe, 256, 0, stream>>>(deg_e, bsum_e, N_EDGES);
    k_scan_bsum<<<1, 128, 0, stream>>>(bsum_e, nbe, e_start, N_EDGES);
    k_scan_final<<<nbe, 1024, 0, stream>>>(deg_e, bsum_e, e_start, N_EDGES);
    k_chunk_sums<<<nbv, 256, 0, stream>>>(deg_v, bsum_v, N_NODES);
    k_scan_bsum<<<1, 128, 0, stream>>>(bsum_v, nbv, v_start, N_NODES);
    k_scan_final<<<nbv, 1024, 0, stream>>>(deg_v, bsum_v, v_start, N_NODES);

    k_fill<<<(NNZ + 255) / 256, 256, 0, stream>>>(nidx, eidx, e_start, v_start,
                                                  cur_e, cur_v, s_node, s_edge);

    k_wcatT<<<640, 256, 0, stream>>>(convW, trW, attnW1, WcatbT);
    k_bcat<<<1, 640, 0, stream>>>(convb, trb, trW, attnW1, attnb1, bcat);

    k_xcast<<<25000, 256, 0, stream>>>((const float4*)x, (ushort4*)xb);

    k_gather_e<<<N_EDGES / 8, 256, 0, stream>>>(s_node, e_start, xb, Binv, agg_eb);

    k_gemm_e<<<(NEPAD / BM) * 10, 256, 0, stream>>>(agg_eb, WcatbT, geb);

    k_attn<<<NPART, 256, 0, stream>>>(s_edge, v_start, geb, Dinv, bcat,
                                      attnW2, attnb2, part);
    k_dsum_final<<<1, 256, 0, stream>>>(part, sw, dsum);

    k_out<<<N_NODES / 4, 256, 0, stream>>>(s_edge, v_start, geb, Dinv, bcat,
                                           ln_g, ln_b, dsum, out);
}